// Round 1
// baseline (3483.147 us; speedup 1.0000x reference)
//
#include <hip/hip_runtime.h>
#include <math.h>

// Problem constants
#define NIMG 8
#define MDIM 512
#define IMGE (MDIM*MDIM)        // 262144 elements per image
#define TOT  (NIMG*IMGE)        // 2097152 total complex elements
#define BETA_K 4096

typedef double2 c64;

struct SelState { unsigned int known; unsigned int rank; unsigned int thrkey; };

__device__ __forceinline__ c64 cmul(const c64 a, const c64 b){
    return make_double2(a.x*b.x - a.y*b.y, a.x*b.y + a.y*b.x);
}

// ---------------- init: T = exp(i*(z/WL)*Q) and 256-entry twiddle table ----------------
__global__ __launch_bounds__(256) void k_init(const float* __restrict__ Q,
                                              const float* __restrict__ zp,
                                              c64* __restrict__ T,
                                              c64* __restrict__ tw){
    int i = blockIdx.x*256 + threadIdx.x;
    if (i < IMGE){
        double a = ((double)zp[0] / 6.37e-07) * (double)Q[i];
        T[i] = make_double2(cos(a), sin(a));
    }
    if (i < 256){
        double a = -6.283185307179586476925286766559 * ((double)i / 512.0);
        tw[i] = make_double2(cos(a), sin(a));
    }
}

// ---------------- 512-point FFT along rows or columns, 8 lines per block ----------------
// radix-2 DIT in LDS, bit-reversed load, natural-order store. In-place safe (src==dst ok).
template<bool INV, bool COLS>
__global__ __launch_bounds__(256) void k_fft(const c64* __restrict__ src,
                                             c64* __restrict__ dst,
                                             const c64* __restrict__ tw,
                                             double scale){
    __shared__ double lre[8][512];
    __shared__ double lim[8][512];
    const int t = threadIdx.x;
    const int blk = blockIdx.x;
    size_t base;
    if (COLS){
        int n  = blk >> 6;            // image
        int c0 = (blk & 63) * 8;      // first column of this block
        base = (size_t)n * IMGE + (size_t)c0;
    } else {
        base = (size_t)blk * (8*512); // 8 consecutive rows, contiguous
    }
    // load with bit-reversal
    #pragma unroll
    for (int it = 0; it < 16; ++it){
        int idx = it*256 + t;
        int ln, e; size_t addr;
        if (COLS){ ln = idx & 7; e = idx >> 3; addr = base + (size_t)ln + (size_t)e*512; }
        else     { ln = idx >> 9; e = idx & 511; addr = base + (size_t)idx; }
        c64 v = src[addr];
        int er = __brev((unsigned)e) >> 23;   // reverse 9 bits
        lre[ln][er] = v.x; lim[ln][er] = v.y;
    }
    __syncthreads();
    // 9 radix-2 stages
    #pragma unroll
    for (int s = 1; s <= 9; ++s){
        int mh = 1 << (s-1);
        int q  = t & (mh-1);
        int a  = ((t >> (s-1)) << s) + q;
        int b  = a + mh;
        c64 w  = tw[q << (9-s)];
        double wr = w.x, wi = INV ? -w.y : w.y;
        #pragma unroll
        for (int ln = 0; ln < 8; ++ln){
            double ur = lre[ln][a], ui = lim[ln][a];
            double vr = lre[ln][b], vi = lim[ln][b];
            double tr = vr*wr - vi*wi;
            double ti = vr*wi + vi*wr;
            lre[ln][a] = ur + tr; lim[ln][a] = ui + ti;
            lre[ln][b] = ur - tr; lim[ln][b] = ui - ti;
        }
        __syncthreads();
    }
    // store (natural order)
    #pragma unroll
    for (int it = 0; it < 16; ++it){
        int idx = it*256 + t;
        int ln, e; size_t addr;
        if (COLS){ ln = idx & 7; e = idx >> 3; addr = base + (size_t)ln + (size_t)e*512; }
        else     { ln = idx >> 9; e = idx & 511; addr = base + (size_t)idx; }
        dst[addr] = make_double2(lre[ln][e]*scale, lim[ln][e]*scale);
    }
}

// ---------------- elementwise kernels (grid = TOT/256 blocks, exact) ----------------
__global__ __launch_bounds__(256) void k_setup1(const float2* __restrict__ H,
                                                c64* __restrict__ W, c64* __restrict__ t1){
    int i = blockIdx.x*256 + threadIdx.x;
    float2 h = H[i];
    W[i]  = make_double2(1.0, 0.0);
    t1[i] = make_double2((double)h.x, (double)h.y);
}

__global__ __launch_bounds__(256) void k_mult(c64* __restrict__ x,
                                              const c64* __restrict__ T, int conj){
    int i = blockIdx.x*256 + threadIdx.x;
    c64 tv = T[i & (IMGE-1)];
    if (conj) tv.y = -tv.y;
    x[i] = cmul(x[i], tv);
}

// W = normalize(convXT + IB); t1 = H*W - convXT   (t1 holds convXT on entry, R on exit)
__global__ __launch_bounds__(256) void k_W_R(const float2* __restrict__ H,
                                             c64* __restrict__ t1,
                                             const c64* __restrict__ IB,
                                             c64* __restrict__ W){
    int i = blockIdx.x*256 + threadIdx.x;
    c64 c = t1[i];
    c64 b = IB[i];
    double sx = c.x + b.x, sy = c.y + b.y;
    double m = sqrt(sx*sx + sy*sy);
    double d = (m == 0.0) ? 1.0 : m;
    c64 w = make_double2(sx/d, sy/d);
    W[i] = w;
    float2 hf = H[i];
    c64 q = cmul(make_double2((double)hf.x, (double)hf.y), w);
    t1[i] = make_double2(q.x - c.x, q.y - c.y);
}

// t1 = H*W - IB   (S = Qc - ifft2(Bmasked))
__global__ __launch_bounds__(256) void k_S(const float2* __restrict__ H,
                                           const c64* __restrict__ W,
                                           const c64* __restrict__ IB,
                                           c64* __restrict__ t1){
    int i = blockIdx.x*256 + threadIdx.x;
    float2 hf = H[i];
    c64 q = cmul(make_double2((double)hf.x, (double)hf.y), W[i]);
    c64 b = IB[i];
    t1[i] = make_double2(q.x - b.x, q.y - b.y);
}

__global__ __launch_bounds__(256) void k_keys(const c64* __restrict__ B,
                                              unsigned int* __restrict__ keys){
    int i = blockIdx.x*256 + threadIdx.x;
    c64 v = B[i];
    double m = sqrt(v.x*v.x + v.y*v.y);
    keys[i] = __float_as_uint((float)m);   // non-negative: bit order == value order
}

__global__ __launch_bounds__(256) void k_mask(c64* __restrict__ B,
                                              const unsigned int* __restrict__ keys,
                                              const SelState* __restrict__ st){
    int i = blockIdx.x*256 + threadIdx.x;
    if (keys[i] < st->thrkey) B[i] = make_double2(0.0, 0.0);
}

__global__ __launch_bounds__(256) void k_X(const c64* __restrict__ t1,
                                           c64* __restrict__ X){
    int i = blockIdx.x*256 + threadIdx.x;
    c64 v = t1[i];
    double m = sqrt(v.x*v.x + v.y*v.y);
    X[i] = (m > 0.1) ? v : make_double2(0.0, 0.0);
}

__global__ __launch_bounds__(256) void k_out(const c64* __restrict__ W,
                                             const c64* __restrict__ B,
                                             float* __restrict__ out){
    int i = blockIdx.x*256 + threadIdx.x;
    out[2*i]   = (float)W[i].x;
    out[2*i+1] = (float)W[i].y;
    float* o2 = out + 2*TOT;
    o2[2*i]   = (float)B[i].x;
    o2[2*i+1] = (float)B[i].y;
}

// ---------------- exact top-BETA threshold: 3-pass radix select on f32 bits ----------------
__global__ void k_sel_init(SelState* st){
    st->known = 0u; st->rank = BETA_K; st->thrkey = 0u;
}

__global__ __launch_bounds__(256) void k_hist(const unsigned int* __restrict__ keys,
                                              unsigned int* __restrict__ hist,
                                              const SelState* __restrict__ st,
                                              int shiftHi, int shift, int dbits){
    __shared__ unsigned int lh[2048];
    int t = threadIdx.x;
    int nd = 1 << dbits;
    for (int b = t; b < nd; b += 256) lh[b] = 0u;
    __syncthreads();
    unsigned known = st->known;
    unsigned msk = (unsigned)((1u << dbits) - 1u);
    for (int i = blockIdx.x*256 + t; i < TOT; i += gridDim.x*256){
        unsigned k = keys[i];
        bool ok = (shiftHi >= 32) || ((k >> shiftHi) == known);
        if (ok) atomicAdd(&lh[(k >> shift) & msk], 1u);
    }
    __syncthreads();
    for (int b = t; b < nd; b += 256){
        unsigned v = lh[b];
        if (v) atomicAdd(&hist[b], v);
    }
}

__global__ __launch_bounds__(256) void k_scan(unsigned int* __restrict__ hist,
                                              SelState* __restrict__ st,
                                              int dbits, int isLast){
    __shared__ unsigned int lh[2048];
    int t = threadIdx.x;
    int nd = 1 << dbits;
    for (int b = t; b < nd; b += 256){ lh[b] = hist[b]; hist[b] = 0u; }
    __syncthreads();
    if (t == 0){
        unsigned rank = st->rank;
        unsigned cum = 0u;
        for (int d = nd-1; d >= 0; --d){
            unsigned c = lh[d];
            if (cum + c >= rank){
                st->rank  = rank - cum;
                unsigned nk = (st->known << dbits) | (unsigned)d;
                st->known = nk;
                if (isLast) st->thrkey = nk;
                break;
            }
            cum += c;
        }
    }
}

// ---------------- orchestration ----------------
// Workspace layout (requires ws_size >= ~133 MB):
//   X   @ 0         (32 MB)   B @ 32 MB   W @ 64 MB   IB @ 96 MB
//   T   @ 128 MB    (4 MB)    tw @ +4 MB  hist @ +4 KB  state
//   keys (8 MB, f32 bits of |B|) overlays IB during its dead window.
//   d_out (32 MB) doubles as the f64 temp t1 until the final convert kernel.
extern "C" void kernel_launch(void* const* d_in, const int* in_sizes, int n_in,
                              void* d_out, int out_size, void* d_ws, size_t ws_size,
                              hipStream_t stream){
    (void)in_sizes; (void)n_in; (void)out_size; (void)ws_size;
    const float2* H = (const float2*)d_in[0];
    const float*  Q = (const float*)d_in[1];
    const float*  zp = (const float*)d_in[2];

    char* ws = (char*)d_ws;
    const size_t A = 33554432; // 32 MB
    c64* X  = (c64*)(ws);
    c64* Bf = (c64*)(ws + A);
    c64* W  = (c64*)(ws + 2*A);
    c64* IB = (c64*)(ws + 3*A);
    c64* T  = (c64*)(ws + 4*A);
    c64* tw = (c64*)(ws + 4*A + 4194304);
    unsigned int* hist = (unsigned int*)(ws + 4*A + 4194304 + 4096);
    SelState* st = (SelState*)(ws + 4*A + 4194304 + 4096 + 8192);
    unsigned int* keys = (unsigned int*)IB;   // overlay (lifetimes disjoint)
    c64* t1 = (c64*)d_out;                    // 32 MB scratch, overwritten by k_out at end

    const int EW = TOT/256;  // 8192 blocks for elementwise kernels

    hipMemsetAsync(hist, 0, 2048*sizeof(unsigned int), stream);
    k_init<<<IMGE/256, 256, 0, stream>>>(Q, zp, T, tw);

    auto fftR = [&](const c64* s, c64* d, int inv){
        if (inv) k_fft<true ,false><<<512,256,0,stream>>>(s,d,tw,1.0/512.0);
        else     k_fft<false,false><<<512,256,0,stream>>>(s,d,tw,1.0);
    };
    auto fftC = [&](const c64* s, c64* d, int inv){
        if (inv) k_fft<true ,true ><<<512,256,0,stream>>>(s,d,tw,1.0/512.0);
        else     k_fft<false,true ><<<512,256,0,stream>>>(s,d,tw,1.0);
    };
    auto fft2 = [&](const c64* s, c64* d, int inv){ fftR(s,d,inv); fftC(d,d,inv); };
    auto doSelect = [&](){
        k_sel_init<<<1,1,0,stream>>>(st);
        k_hist<<<256,256,0,stream>>>(keys,hist,st,32,21,11);
        k_scan<<<1,256,0,stream>>>(hist,st,11,0);
        k_hist<<<256,256,0,stream>>>(keys,hist,st,21,10,11);
        k_scan<<<1,256,0,stream>>>(hist,st,11,0);
        k_hist<<<256,256,0,stream>>>(keys,hist,st,10,0,10);
        k_scan<<<1,256,0,stream>>>(hist,st,10,1);
    };

    // ---- iteration 1: X=0 => convXT=0, B0=fft2(ones)=exact delta => W=1, R=H ----
    k_setup1<<<EW,256,0,stream>>>(H, W, t1);
    fft2(t1, Bf, 0);                               // B = fft2(R)
    k_keys<<<EW,256,0,stream>>>(Bf, keys);
    doSelect();
    k_mask<<<EW,256,0,stream>>>(Bf, keys, st);
    fftR(Bf, IB, 1); fftC(IB, IB, 1);              // IB = ifft2(B_masked)
    k_S<<<EW,256,0,stream>>>(H, W, IB, t1);        // S = H*W - IB
    fft2(t1, t1, 0);
    k_mult<<<EW,256,0,stream>>>(t1, T, 1);         // * conj(T)
    fft2(t1, t1, 1);                               // inp1
    k_X<<<EW,256,0,stream>>>(t1, X);

    // ---- iterations 2..6 ----
    for (int iter = 2; iter <= 6; ++iter){
        fft2(X, t1, 0);
        k_mult<<<EW,256,0,stream>>>(t1, T, 0);
        fft2(t1, t1, 1);                           // t1 = convXT
        k_W_R<<<EW,256,0,stream>>>(H, t1, IB, W);  // W update; t1 = R
        fft2(t1, Bf, 0);                           // B = fft2(R)
        k_keys<<<EW,256,0,stream>>>(Bf, keys);
        doSelect();
        k_mask<<<EW,256,0,stream>>>(Bf, keys, st);
        if (iter < 6){
            fftR(Bf, IB, 1); fftC(IB, IB, 1);      // IB = ifft2(B_masked), reused next iter
            k_S<<<EW,256,0,stream>>>(H, W, IB, t1);
            fft2(t1, t1, 0);
            k_mult<<<EW,256,0,stream>>>(t1, T, 1);
            fft2(t1, t1, 1);
            k_X<<<EW,256,0,stream>>>(t1, X);
        }
    }

    k_out<<<EW,256,0,stream>>>(W, Bf, (float*)d_out);
}

// Round 2
// 2366.917 us; speedup vs baseline: 1.4716x; 1.4716x over previous
//
#include <hip/hip_runtime.h>
#include <math.h>

// Problem constants
#define NIMG 8
#define MDIM 512
#define IMGE (MDIM*MDIM)        // 262144 elements per image
#define TOT  (NIMG*IMGE)        // 2097152 total complex elements
#define BETA_K 4096

typedef double2 c64;

struct SelState { unsigned int known; unsigned int rank; unsigned int thrkey; };

__device__ __forceinline__ c64 cmul(const c64 a, const c64 b){
    return make_double2(a.x*b.x - a.y*b.y, a.x*b.y + a.y*b.x);
}

// ---------------- init: T = exp(i*(z/WL)*Q) and 256-entry twiddle table ----------------
__global__ __launch_bounds__(256) void k_init(const float* __restrict__ Q,
                                              const float* __restrict__ zp,
                                              c64* __restrict__ T,
                                              c64* __restrict__ tw){
    int i = blockIdx.x*256 + threadIdx.x;
    if (i < IMGE){
        double a = ((double)zp[0] / 6.37e-07) * (double)Q[i];
        T[i] = make_double2(cos(a), sin(a));
    }
    if (i < 256){
        double a = -6.283185307179586476925286766559 * ((double)i / 512.0);
        tw[i] = make_double2(cos(a), sin(a));
    }
}

// ---------------- 512-point FFT along rows or columns, 8 lines per block ----------------
// radix-2 DIT in LDS, bit-reversed load, natural-order store. In-place safe (src==dst ok).
template<bool INV, bool COLS>
__global__ __launch_bounds__(256) void k_fft(const c64* __restrict__ src,
                                             c64* __restrict__ dst,
                                             const c64* __restrict__ tw,
                                             double scale){
    __shared__ double lre[8][512];
    __shared__ double lim[8][512];
    const int t = threadIdx.x;
    const int blk = blockIdx.x;
    size_t base;
    if (COLS){
        int n  = blk >> 6;            // image
        int c0 = (blk & 63) * 8;      // first column of this block
        base = (size_t)n * IMGE + (size_t)c0;
    } else {
        base = (size_t)blk * (8*512); // 8 consecutive rows, contiguous
    }
    // load with bit-reversal
    #pragma unroll
    for (int it = 0; it < 16; ++it){
        int idx = it*256 + t;
        int ln, e; size_t addr;
        if (COLS){ ln = idx & 7; e = idx >> 3; addr = base + (size_t)ln + (size_t)e*512; }
        else     { ln = idx >> 9; e = idx & 511; addr = base + (size_t)idx; }
        c64 v = src[addr];
        int er = __brev((unsigned)e) >> 23;   // reverse 9 bits
        lre[ln][er] = v.x; lim[ln][er] = v.y;
    }
    __syncthreads();
    // 9 radix-2 stages
    #pragma unroll
    for (int s = 1; s <= 9; ++s){
        int mh = 1 << (s-1);
        int q  = t & (mh-1);
        int a  = ((t >> (s-1)) << s) + q;
        int b  = a + mh;
        c64 w  = tw[q << (9-s)];
        double wr = w.x, wi = INV ? -w.y : w.y;
        #pragma unroll
        for (int ln = 0; ln < 8; ++ln){
            double ur = lre[ln][a], ui = lim[ln][a];
            double vr = lre[ln][b], vi = lim[ln][b];
            double tr = vr*wr - vi*wi;
            double ti = vr*wi + vi*wr;
            lre[ln][a] = ur + tr; lim[ln][a] = ui + ti;
            lre[ln][b] = ur - tr; lim[ln][b] = ui - ti;
        }
        __syncthreads();
    }
    // store (natural order)
    #pragma unroll
    for (int it = 0; it < 16; ++it){
        int idx = it*256 + t;
        int ln, e; size_t addr;
        if (COLS){ ln = idx & 7; e = idx >> 3; addr = base + (size_t)ln + (size_t)e*512; }
        else     { ln = idx >> 9; e = idx & 511; addr = base + (size_t)idx; }
        dst[addr] = make_double2(lre[ln][e]*scale, lim[ln][e]*scale);
    }
}

// ---------------- elementwise kernels (grid = TOT/256 blocks, exact) ----------------
__global__ __launch_bounds__(256) void k_setup1(const float2* __restrict__ H,
                                                c64* __restrict__ W, c64* __restrict__ t1){
    int i = blockIdx.x*256 + threadIdx.x;
    float2 h = H[i];
    W[i]  = make_double2(1.0, 0.0);
    t1[i] = make_double2((double)h.x, (double)h.y);
}

__global__ __launch_bounds__(256) void k_mult(c64* __restrict__ x,
                                              const c64* __restrict__ T, int conj){
    int i = blockIdx.x*256 + threadIdx.x;
    c64 tv = T[i & (IMGE-1)];
    if (conj) tv.y = -tv.y;
    x[i] = cmul(x[i], tv);
}

// W = normalize(convXT + IB); t1 = H*W - convXT   (t1 holds convXT on entry, R on exit)
__global__ __launch_bounds__(256) void k_W_R(const float2* __restrict__ H,
                                             c64* __restrict__ t1,
                                             const c64* __restrict__ IB,
                                             c64* __restrict__ W){
    int i = blockIdx.x*256 + threadIdx.x;
    c64 c = t1[i];
    c64 b = IB[i];
    double sx = c.x + b.x, sy = c.y + b.y;
    double m = sqrt(sx*sx + sy*sy);
    double d = (m == 0.0) ? 1.0 : m;
    c64 w = make_double2(sx/d, sy/d);
    W[i] = w;
    float2 hf = H[i];
    c64 q = cmul(make_double2((double)hf.x, (double)hf.y), w);
    t1[i] = make_double2(q.x - c.x, q.y - c.y);
}

// t1 = H*W - IB   (S = Qc - ifft2(Bmasked))
__global__ __launch_bounds__(256) void k_S(const float2* __restrict__ H,
                                           const c64* __restrict__ W,
                                           const c64* __restrict__ IB,
                                           c64* __restrict__ t1){
    int i = blockIdx.x*256 + threadIdx.x;
    float2 hf = H[i];
    c64 q = cmul(make_double2((double)hf.x, (double)hf.y), W[i]);
    c64 b = IB[i];
    t1[i] = make_double2(q.x - b.x, q.y - b.y);
}

__global__ __launch_bounds__(256) void k_keys(const c64* __restrict__ B,
                                              unsigned int* __restrict__ keys){
    int i = blockIdx.x*256 + threadIdx.x;
    c64 v = B[i];
    double m = sqrt(v.x*v.x + v.y*v.y);
    keys[i] = __float_as_uint((float)m);   // non-negative: bit order == value order
}

__global__ __launch_bounds__(256) void k_mask(c64* __restrict__ B,
                                              const unsigned int* __restrict__ keys,
                                              const SelState* __restrict__ st){
    int i = blockIdx.x*256 + threadIdx.x;
    if (keys[i] < st->thrkey) B[i] = make_double2(0.0, 0.0);
}

__global__ __launch_bounds__(256) void k_X(const c64* __restrict__ t1,
                                           c64* __restrict__ X){
    int i = blockIdx.x*256 + threadIdx.x;
    c64 v = t1[i];
    double m = sqrt(v.x*v.x + v.y*v.y);
    X[i] = (m > 0.1) ? v : make_double2(0.0, 0.0);
}

__global__ __launch_bounds__(256) void k_out(const c64* __restrict__ W,
                                             const c64* __restrict__ B,
                                             float* __restrict__ out){
    int i = blockIdx.x*256 + threadIdx.x;
    out[2*i]   = (float)W[i].x;
    out[2*i+1] = (float)W[i].y;
    float* o2 = out + 2*TOT;
    o2[2*i]   = (float)B[i].x;
    o2[2*i+1] = (float)B[i].y;
}

// ---------------- exact top-BETA threshold: 3-pass radix select on f32 bits ----------------
__global__ void k_sel_init(SelState* st){
    st->known = 0u; st->rank = BETA_K; st->thrkey = 0u;
}

__global__ __launch_bounds__(256) void k_hist(const unsigned int* __restrict__ keys,
                                              unsigned int* __restrict__ hist,
                                              const SelState* __restrict__ st,
                                              int shiftHi, int shift, int dbits){
    __shared__ unsigned int lh[2048];
    int t = threadIdx.x;
    int nd = 1 << dbits;
    for (int b = t; b < nd; b += 256) lh[b] = 0u;
    __syncthreads();
    unsigned known = st->known;
    unsigned msk = (unsigned)((1u << dbits) - 1u);
    for (int i = blockIdx.x*256 + t; i < TOT; i += gridDim.x*256){
        unsigned k = keys[i];
        bool ok = (shiftHi >= 32) || ((k >> shiftHi) == known);
        if (ok) atomicAdd(&lh[(k >> shift) & msk], 1u);
    }
    __syncthreads();
    for (int b = t; b < nd; b += 256){
        unsigned v = lh[b];
        if (v) atomicAdd(&hist[b], v);
    }
}

// Parallel radix-select scan: 256 threads, each owns nd/256 bins in registers.
// Suffix-scan of chunk totals (Hillis-Steele in LDS), then the unique thread
// with s[t+1] < rank <= s[t] walks its own bins top-down (exact tie semantics
// identical to the serial version). Also zeroes hist for the next pass.
__global__ __launch_bounds__(256) void k_scan(unsigned int* __restrict__ hist,
                                              SelState* __restrict__ st,
                                              int dbits, int isLast){
    __shared__ unsigned int s[256];
    const int t = threadIdx.x;
    const int nd = 1 << dbits;
    const int per = nd >> 8;            // 8 (11 bits) or 4 (10 bits)
    unsigned c[8];
    unsigned local = 0u;
    const int b0 = t * per;
    #pragma unroll
    for (int j = 0; j < 8; ++j){
        unsigned v = 0u;
        if (j < per){ v = hist[b0 + j]; hist[b0 + j] = 0u; }
        c[j] = v; local += v;
    }
    unsigned rank = st->rank;           // broadcast read
    s[t] = local;
    __syncthreads();
    // inclusive suffix scan: s[t] = sum_{j>=t} local[j]
    #pragma unroll
    for (int off = 1; off < 256; off <<= 1){
        unsigned add = (t + off < 256) ? s[t + off] : 0u;
        __syncthreads();
        s[t] += add;
        __syncthreads();
    }
    unsigned stot   = s[t];
    unsigned sAfter = (t < 255) ? s[t + 1] : 0u;
    if (sAfter < rank && stot >= rank){
        unsigned cum = sAfter;          // sum of all bins strictly above current walk pos
        int j = per - 1;
        #pragma unroll
        for (int k = 7; k >= 0; --k){
            if (k > per - 1) continue;
            j = k;
            if (cum + c[k] >= rank) break;
            cum += c[k];
        }
        st->rank = rank - cum;
        unsigned nk = (st->known << dbits) | (unsigned)(b0 + j);
        st->known = nk;
        if (isLast) st->thrkey = nk;
    }
}

// ---------------- orchestration ----------------
// Workspace layout (requires ws_size >= ~133 MB):
//   X   @ 0         (32 MB)   B @ 32 MB   W @ 64 MB   IB @ 96 MB
//   T   @ 128 MB    (4 MB)    tw @ +4 MB  hist @ +4 KB  state
//   keys (8 MB, f32 bits of |B|) overlays IB during its dead window.
//   d_out (32 MB) doubles as the f64 temp t1 until the final convert kernel.
extern "C" void kernel_launch(void* const* d_in, const int* in_sizes, int n_in,
                              void* d_out, int out_size, void* d_ws, size_t ws_size,
                              hipStream_t stream){
    (void)in_sizes; (void)n_in; (void)out_size; (void)ws_size;
    const float2* H = (const float2*)d_in[0];
    const float*  Q = (const float*)d_in[1];
    const float*  zp = (const float*)d_in[2];

    char* ws = (char*)d_ws;
    const size_t A = 33554432; // 32 MB
    c64* X  = (c64*)(ws);
    c64* Bf = (c64*)(ws + A);
    c64* W  = (c64*)(ws + 2*A);
    c64* IB = (c64*)(ws + 3*A);
    c64* T  = (c64*)(ws + 4*A);
    c64* tw = (c64*)(ws + 4*A + 4194304);
    unsigned int* hist = (unsigned int*)(ws + 4*A + 4194304 + 4096);
    SelState* st = (SelState*)(ws + 4*A + 4194304 + 4096 + 8192);
    unsigned int* keys = (unsigned int*)IB;   // overlay (lifetimes disjoint)
    c64* t1 = (c64*)d_out;                    // 32 MB scratch, overwritten by k_out at end

    const int EW = TOT/256;  // 8192 blocks for elementwise kernels

    hipMemsetAsync(hist, 0, 2048*sizeof(unsigned int), stream);
    k_init<<<IMGE/256, 256, 0, stream>>>(Q, zp, T, tw);

    auto fftR = [&](const c64* s, c64* d, int inv){
        if (inv) k_fft<true ,false><<<512,256,0,stream>>>(s,d,tw,1.0/512.0);
        else     k_fft<false,false><<<512,256,0,stream>>>(s,d,tw,1.0);
    };
    auto fftC = [&](const c64* s, c64* d, int inv){
        if (inv) k_fft<true ,true ><<<512,256,0,stream>>>(s,d,tw,1.0/512.0);
        else     k_fft<false,true ><<<512,256,0,stream>>>(s,d,tw,1.0);
    };
    auto fft2 = [&](const c64* s, c64* d, int inv){ fftR(s,d,inv); fftC(d,d,inv); };
    auto doSelect = [&](){
        k_sel_init<<<1,1,0,stream>>>(st);
        k_hist<<<256,256,0,stream>>>(keys,hist,st,32,21,11);
        k_scan<<<1,256,0,stream>>>(hist,st,11,0);
        k_hist<<<256,256,0,stream>>>(keys,hist,st,21,10,11);
        k_scan<<<1,256,0,stream>>>(hist,st,11,0);
        k_hist<<<256,256,0,stream>>>(keys,hist,st,10,0,10);
        k_scan<<<1,256,0,stream>>>(hist,st,10,1);
    };

    // ---- iteration 1: X=0 => convXT=0, B0=fft2(ones)=exact delta => W=1, R=H ----
    k_setup1<<<EW,256,0,stream>>>(H, W, t1);
    fft2(t1, Bf, 0);                               // B = fft2(R)
    k_keys<<<EW,256,0,stream>>>(Bf, keys);
    doSelect();
    k_mask<<<EW,256,0,stream>>>(Bf, keys, st);
    fftR(Bf, IB, 1); fftC(IB, IB, 1);              // IB = ifft2(B_masked)
    k_S<<<EW,256,0,stream>>>(H, W, IB, t1);        // S = H*W - IB
    fft2(t1, t1, 0);
    k_mult<<<EW,256,0,stream>>>(t1, T, 1);         // * conj(T)
    fft2(t1, t1, 1);                               // inp1
    k_X<<<EW,256,0,stream>>>(t1, X);

    // ---- iterations 2..6 ----
    for (int iter = 2; iter <= 6; ++iter){
        fft2(X, t1, 0);
        k_mult<<<EW,256,0,stream>>>(t1, T, 0);
        fft2(t1, t1, 1);                           // t1 = convXT
        k_W_R<<<EW,256,0,stream>>>(H, t1, IB, W);  // W update; t1 = R
        fft2(t1, Bf, 0);                           // B = fft2(R)
        k_keys<<<EW,256,0,stream>>>(Bf, keys);
        doSelect();
        k_mask<<<EW,256,0,stream>>>(Bf, keys, st);
        if (iter < 6){
            fftR(Bf, IB, 1); fftC(IB, IB, 1);      // IB = ifft2(B_masked), reused next iter
            k_S<<<EW,256,0,stream>>>(H, W, IB, t1);
            fft2(t1, t1, 0);
            k_mult<<<EW,256,0,stream>>>(t1, T, 1);
            fft2(t1, t1, 1);
            k_X<<<EW,256,0,stream>>>(t1, X);
        }
    }

    k_out<<<EW,256,0,stream>>>(W, Bf, (float*)d_out);
}

// Round 4
// 1110.263 us; speedup vs baseline: 3.1372x; 2.1319x over previous
//
#include <hip/hip_runtime.h>
#include <math.h>

// Problem constants
#define NIMG 8
#define MDIM 512
#define IMGE (MDIM*MDIM)        // 262144 per image
#define TOT  (NIMG*IMGE)        // 2097152 complex elements
#define BETA_K 4096
#define LAMD 0.1

typedef double2 c64;

struct SelState { unsigned int known; unsigned int rank; unsigned int thrkey; };

// ---------------- LDS addressing: 8 lines x 512, XOR swizzle (bank-minimal for strides 1/8/64) ----------------
__device__ __forceinline__ int SW(int ln, int e){
    return (ln << 9) + (e ^ (((e >> 4) ^ (ln << 1)) & 15));
}
__device__ __forceinline__ int rev8(int n){   // base-8 digit reversal of 9-bit index
    return ((n & 7) << 6) | (n & 56) | (n >> 6);
}

// ---------------- 8-point DFT in registers. INV=true: conjugate (inverse) ----------------
template<bool INV>
__device__ __forceinline__ void dft8(double* xr, double* xi){
    const double C = 0.70710678118654752440;
    // even DFT4 (y0,y2,y4,y6)
    double t0r=xr[0]+xr[4], t0i=xi[0]+xi[4];
    double t1r=xr[0]-xr[4], t1i=xi[0]-xi[4];
    double t2r=xr[2]+xr[6], t2i=xi[2]+xi[6];
    double t3r=xr[2]-xr[6], t3i=xi[2]-xi[6];
    double m3r = INV ? -t3i : t3i;            // (-+i)*t3
    double m3i = INV ?  t3r : -t3r;
    double E0r=t0r+t2r, E0i=t0i+t2i;
    double E2r=t0r-t2r, E2i=t0i-t2i;
    double E1r=t1r+m3r, E1i=t1i+m3i;
    double E3r=t1r-m3r, E3i=t1i-m3i;
    // odd DFT4 (y1,y3,y5,y7)
    double u0r=xr[1]+xr[5], u0i=xi[1]+xi[5];
    double u1r=xr[1]-xr[5], u1i=xi[1]-xi[5];
    double u2r=xr[3]+xr[7], u2i=xi[3]+xi[7];
    double u3r=xr[3]-xr[7], u3i=xi[3]-xi[7];
    double n3r = INV ? -u3i : u3i;
    double n3i = INV ?  u3r : -u3r;
    double O0r=u0r+u2r, O0i=u0i+u2i;
    double O2r=u0r-u2r, O2i=u0i-u2i;
    double O1r=u1r+n3r, O1i=u1i+n3i;
    double O3r=u1r-n3r, O3i=u1i-n3i;
    // W8^k twiddles on odd outputs
    double W1r = INV ? C*(O1r - O1i) : C*(O1r + O1i);
    double W1i = INV ? C*(O1r + O1i) : C*(O1i - O1r);
    double W2r = INV ? -O2i : O2i;
    double W2i = INV ?  O2r : -O2r;
    double W3r = INV ? -C*(O3r + O3i) : C*(O3i - O3r);
    double W3i = INV ?  C*(O3r - O3i) : -C*(O3r + O3i);
    xr[0]=E0r+O0r; xi[0]=E0i+O0i;  xr[4]=E0r-O0r; xi[4]=E0i-O0i;
    xr[1]=E1r+W1r; xi[1]=E1i+W1i;  xr[5]=E1r-W1r; xi[5]=E1i-W1i;
    xr[2]=E2r+W2r; xi[2]=E2i+W2i;  xr[6]=E2r-W2r; xi[6]=E2i-W2i;
    xr[3]=E3r+W3r; xi[3]=E3i+W3i;  xr[7]=E3r-W3r; xi[7]=E3i-W3i;
}

// ---------------- radix-8 DIT: digit-reversed LDS input -> natural order ----------------
// syncs at each stage head (covers preceding writes); caller syncs after the call.
template<bool INV>
__device__ void r8_dit(double* re, double* im, const c64* __restrict__ tw){
    const int t = threadIdx.x;
    const int w = t & 63;
    const int l0 = t >> 6;
    // stage 0: p_k = 8w + k, no twiddle
    __syncthreads();
    #pragma unroll
    for (int h = 0; h < 2; ++h){
        const int ln = l0 + 4*h;
        double xr[8], xi[8];
        #pragma unroll
        for (int k = 0; k < 8; ++k){ int p = SW(ln, 8*w + k); xr[k]=re[p]; xi[k]=im[p]; }
        dft8<INV>(xr, xi);
        #pragma unroll
        for (int k = 0; k < 8; ++k){ int p = SW(ln, 8*w + k); re[p]=xr[k]; im[p]=xi[k]; }
    }
    // stage 1: g=w>>3, j=w&7: p_k = 64g + j + 8k, tw[8jk]
    {
        const int g = w >> 3, j = w & 7;
        double wr[8], wi[8];
        #pragma unroll
        for (int k = 1; k < 8; ++k){ c64 tv = tw[8*j*k]; wr[k]=tv.x; wi[k]= INV ? -tv.y : tv.y; }
        __syncthreads();
        #pragma unroll
        for (int h = 0; h < 2; ++h){
            const int ln = l0 + 4*h;
            double xr[8], xi[8];
            #pragma unroll
            for (int k = 0; k < 8; ++k){
                int p = SW(ln, 64*g + j + 8*k); double ar=re[p], ai=im[p];
                if (k == 0){ xr[0]=ar; xi[0]=ai; }
                else { xr[k]=ar*wr[k]-ai*wi[k]; xi[k]=ar*wi[k]+ai*wr[k]; }
            }
            dft8<INV>(xr, xi);
            #pragma unroll
            for (int k = 0; k < 8; ++k){ int p = SW(ln, 64*g + j + 8*k); re[p]=xr[k]; im[p]=xi[k]; }
        }
    }
    // stage 2: j=w: p_k = j + 64k, tw[jk]
    {
        const int j = w;
        double wr[8], wi[8];
        #pragma unroll
        for (int k = 1; k < 8; ++k){ c64 tv = tw[j*k]; wr[k]=tv.x; wi[k]= INV ? -tv.y : tv.y; }
        __syncthreads();
        #pragma unroll
        for (int h = 0; h < 2; ++h){
            const int ln = l0 + 4*h;
            double xr[8], xi[8];
            #pragma unroll
            for (int k = 0; k < 8; ++k){
                int p = SW(ln, j + 64*k); double ar=re[p], ai=im[p];
                if (k == 0){ xr[0]=ar; xi[0]=ai; }
                else { xr[k]=ar*wr[k]-ai*wi[k]; xi[k]=ar*wi[k]+ai*wr[k]; }
            }
            dft8<INV>(xr, xi);
            #pragma unroll
            for (int k = 0; k < 8; ++k){ int p = SW(ln, j + 64*k); re[p]=xr[k]; im[p]=xi[k]; }
        }
    }
}

// ---------------- radix-8 DIF: natural LDS input -> digit-reversed order ----------------
template<bool INV>
__device__ void r8_dif(double* re, double* im, const c64* __restrict__ tw){
    const int t = threadIdx.x;
    const int w = t & 63;
    const int l0 = t >> 6;
    // stage A: p_k = w + 64k, post-twiddle tw[w*k]
    {
        const int j = w;
        double wr[8], wi[8];
        #pragma unroll
        for (int k = 1; k < 8; ++k){ c64 tv = tw[j*k]; wr[k]=tv.x; wi[k]= INV ? -tv.y : tv.y; }
        __syncthreads();
        #pragma unroll
        for (int h = 0; h < 2; ++h){
            const int ln = l0 + 4*h;
            double xr[8], xi[8];
            #pragma unroll
            for (int k = 0; k < 8; ++k){ int p = SW(ln, j + 64*k); xr[k]=re[p]; xi[k]=im[p]; }
            dft8<INV>(xr, xi);
            #pragma unroll
            for (int k = 0; k < 8; ++k){
                int p = SW(ln, j + 64*k);
                if (k == 0){ re[p]=xr[0]; im[p]=xi[0]; }
                else { re[p]=xr[k]*wr[k]-xi[k]*wi[k]; im[p]=xr[k]*wi[k]+xi[k]*wr[k]; }
            }
        }
    }
    // stage B: g=w>>3, j=w&7: p_k = 64g + j + 8k, post tw[8jk]
    {
        const int g = w >> 3, j = w & 7;
        double wr[8], wi[8];
        #pragma unroll
        for (int k = 1; k < 8; ++k){ c64 tv = tw[8*j*k]; wr[k]=tv.x; wi[k]= INV ? -tv.y : tv.y; }
        __syncthreads();
        #pragma unroll
        for (int h = 0; h < 2; ++h){
            const int ln = l0 + 4*h;
            double xr[8], xi[8];
            #pragma unroll
            for (int k = 0; k < 8; ++k){ int p = SW(ln, 64*g + j + 8*k); xr[k]=re[p]; xi[k]=im[p]; }
            dft8<INV>(xr, xi);
            #pragma unroll
            for (int k = 0; k < 8; ++k){
                int p = SW(ln, 64*g + j + 8*k);
                if (k == 0){ re[p]=xr[0]; im[p]=xi[0]; }
                else { re[p]=xr[k]*wr[k]-xi[k]*wi[k]; im[p]=xr[k]*wi[k]+xi[k]*wr[k]; }
            }
        }
    }
    // stage C: p_k = 8w + k, no twiddle
    __syncthreads();
    #pragma unroll
    for (int h = 0; h < 2; ++h){
        const int ln = l0 + 4*h;
        double xr[8], xi[8];
        #pragma unroll
        for (int k = 0; k < 8; ++k){ int p = SW(ln, 8*w + k); xr[k]=re[p]; xi[k]=im[p]; }
        dft8<INV>(xr, xi);
        #pragma unroll
        for (int k = 0; k < 8; ++k){ int p = SW(ln, 8*w + k); re[p]=xr[k]; im[p]=xi[k]; }
    }
}

// ---------------- load/store phases ----------------
// ROW kernels: 8 consecutive memory rows per block; addr = base + idx.
// COL kernels: 8 consecutive columns of one image; addr = base + ln + e*512.
__device__ __forceinline__ void row_load(const c64* __restrict__ src, size_t base, double* re, double* im){
    const int t = threadIdx.x;
    #pragma unroll
    for (int it = 0; it < 16; ++it){
        int idx = it*256 + t; int ln = idx >> 9, e = idx & 511;
        c64 v = src[base + idx];
        int p = SW(ln, rev8(e));
        re[p] = v.x; im[p] = v.y;
    }
}
__device__ __forceinline__ void col_load(const c64* __restrict__ src, size_t base, double* re, double* im){
    const int t = threadIdx.x;
    #pragma unroll
    for (int it = 0; it < 16; ++it){
        int idx = it*256 + t; int ln = idx & 7, e = idx >> 3;
        c64 v = src[base + ln + (size_t)e*512];
        int p = SW(ln, rev8(e));
        re[p] = v.x; im[p] = v.y;
    }
}

// ---------------- init: T = exp(i*(z/WL)*Q), 512-entry twiddle table ----------------
__global__ __launch_bounds__(256) void k_init(const float* __restrict__ Q,
                                              const float* __restrict__ zp,
                                              c64* __restrict__ T,
                                              c64* __restrict__ tw){
    int i = blockIdx.x*256 + threadIdx.x;
    if (i < IMGE){
        double a = ((double)zp[0] / 6.37e-07) * (double)Q[i];
        T[i] = make_double2(cos(a), sin(a));
    }
    if (i < 512){
        double a = -6.283185307179586476925286766559 * ((double)i / 512.0);
        tw[i] = make_double2(cos(a), sin(a));
    }
}

// ---------------- k_colF: forward col FFT of H (f32 in) -> t2 ----------------
__global__ __launch_bounds__(256) void k_colF(const float2* __restrict__ H,
                                              c64* __restrict__ t2,
                                              const c64* __restrict__ tw){
    __shared__ double re[4096]; __shared__ double im[4096];
    const int t = threadIdx.x, blk = blockIdx.x;
    const size_t base = (size_t)(blk >> 6) * IMGE + (size_t)(blk & 63) * 8;
    #pragma unroll
    for (int it = 0; it < 16; ++it){
        int idx = it*256 + t; int ln = idx & 7, e = idx >> 3;
        float2 v = H[base + ln + (size_t)e*512];
        int p = SW(ln, rev8(e));
        re[p] = (double)v.x; im[p] = (double)v.y;
    }
    r8_dit<false>(re, im, tw);
    __syncthreads();
    #pragma unroll
    for (int it = 0; it < 16; ++it){
        int idx = it*256 + t; int ln = idx & 7, e = idx >> 3;
        int p = SW(ln, e);
        t2[base + ln + (size_t)e*512] = make_double2(re[p], im[p]);
    }
}

// ---------------- k_rowT: rowF -> *T(u,v) (or conj) -> rowI, scale 1/512 ----------------
template<bool CONJ>
__global__ __launch_bounds__(256) void k_rowT(c64* __restrict__ t2,
                                              const c64* __restrict__ T,
                                              const c64* __restrict__ tw){
    __shared__ double re[4096]; __shared__ double im[4096];
    const int t = threadIdx.x, blk = blockIdx.x;
    const size_t base = (size_t)blk * 4096;
    row_load(t2, base, re, im);
    r8_dit<false>(re, im, tw);
    __syncthreads();
    #pragma unroll
    for (int it = 0; it < 16; ++it){
        int idx = it*256 + t; int ln = idx >> 9, e = idx & 511;
        int u = ((blk & 63) * 8 + ln) & 511;
        c64 tv = T[u*512 + e];
        double ti = CONJ ? -tv.y : tv.y;
        int p = SW(ln, e);
        double xr = re[p], xi = im[p];
        re[p] = xr*tv.x - xi*ti;
        im[p] = xr*ti + xi*tv.x;
    }
    r8_dif<true>(re, im, tw);
    __syncthreads();
    const double sc = 1.0/512.0;
    #pragma unroll
    for (int it = 0; it < 16; ++it){
        int idx = it*256 + t; int ln = idx >> 9, e = idx & 511;
        int p = SW(ln, rev8(e));
        t2[base + idx] = make_double2(re[p]*sc, im[p]*sc);
    }
}

// ---------------- k_colWR: colI(convXT) -> W=normalize(convXT+IB) -> R=H*W-convXT -> colF(R) ----------------
template<bool FINAL>
__global__ __launch_bounds__(256) void k_colWR(c64* __restrict__ t2,
                                               const float2* __restrict__ H,
                                               const c64* __restrict__ IB,
                                               void* __restrict__ Wout,
                                               const c64* __restrict__ tw){
    __shared__ double re[4096]; __shared__ double im[4096];
    const int t = threadIdx.x, blk = blockIdx.x;
    const size_t base = (size_t)(blk >> 6) * IMGE + (size_t)(blk & 63) * 8;
    col_load(t2, base, re, im);
    r8_dit<true>(re, im, tw);     // inverse col FFT (unscaled)
    __syncthreads();
    const double sc = 1.0/512.0;
    #pragma unroll
    for (int it = 0; it < 16; ++it){
        int idx = it*256 + t; int ln = idx & 7, e = idx >> 3;
        size_t addr = base + ln + (size_t)e*512;
        int p = SW(ln, e);
        double cr = re[p]*sc, ci = im[p]*sc;      // convXT
        c64 b = IB[addr];
        double sx = cr + b.x, sy = ci + b.y;
        double m = sqrt(sx*sx + sy*sy);
        double d = (m == 0.0) ? 1.0 : m;
        double wx = sx/d, wy = sy/d;
        if (FINAL) ((float2*)Wout)[addr] = make_float2((float)wx, (float)wy);
        else       ((c64*)Wout)[addr]    = make_double2(wx, wy);
        float2 h = H[addr];
        re[p] = (double)h.x*wx - (double)h.y*wy - cr;   // R = H*W - convXT
        im[p] = (double)h.x*wy + (double)h.y*wx - ci;
    }
    r8_dif<false>(re, im, tw);    // forward col FFT of R
    __syncthreads();
    #pragma unroll
    for (int it = 0; it < 16; ++it){
        int idx = it*256 + t; int ln = idx & 7, e = idx >> 3;
        int p = SW(ln, rev8(e));
        t2[base + ln + (size_t)e*512] = make_double2(re[p], im[p]);
    }
}

// ---------------- k_rowB: rowF -> B (natural full-freq) + f32 keys ----------------
__global__ __launch_bounds__(256) void k_rowB(const c64* __restrict__ t2,
                                              c64* __restrict__ B,
                                              unsigned int* __restrict__ keys,
                                              const c64* __restrict__ tw){
    __shared__ double re[4096]; __shared__ double im[4096];
    const int t = threadIdx.x, blk = blockIdx.x;
    const size_t base = (size_t)blk * 4096;
    row_load(t2, base, re, im);
    r8_dit<false>(re, im, tw);
    __syncthreads();
    #pragma unroll
    for (int it = 0; it < 16; ++it){
        int idx = it*256 + t; int ln = idx >> 9, e = idx & 511;
        int p = SW(ln, e);
        double xr = re[p], xi = im[p];
        B[base + idx] = make_double2(xr, xi);
        keys[base + idx] = __float_as_uint((float)sqrt(xr*xr + xi*xi));
    }
}

// ---------------- k_rowMI: mask(B) -> rowI (scale 1/512) -> t2 ----------------
__global__ __launch_bounds__(256) void k_rowMI(const c64* __restrict__ B,
                                               const unsigned int* __restrict__ keys,
                                               const SelState* __restrict__ st,
                                               c64* __restrict__ t2,
                                               const c64* __restrict__ tw){
    __shared__ double re[4096]; __shared__ double im[4096];
    const int t = threadIdx.x, blk = blockIdx.x;
    const size_t base = (size_t)blk * 4096;
    const unsigned int thr = st->thrkey;
    #pragma unroll
    for (int it = 0; it < 16; ++it){
        int idx = it*256 + t; int ln = idx >> 9, e = idx & 511;
        c64 v = B[base + idx];
        if (keys[base + idx] < thr) v = make_double2(0.0, 0.0);
        int p = SW(ln, rev8(e));
        re[p] = v.x; im[p] = v.y;
    }
    r8_dit<true>(re, im, tw);
    __syncthreads();
    const double sc = 1.0/512.0;
    #pragma unroll
    for (int it = 0; it < 16; ++it){
        int idx = it*256 + t; int ln = idx >> 9, e = idx & 511;
        int p = SW(ln, e);
        t2[base + idx] = make_double2(re[p]*sc, im[p]*sc);
    }
}

// ---------------- k_colSIB: colI -> IB store, S = Qc - IB -> colF(S) ----------------
template<bool WONE>
__global__ __launch_bounds__(256) void k_colSIB(c64* __restrict__ t2,
                                                const float2* __restrict__ H,
                                                const c64* __restrict__ Wa,
                                                c64* __restrict__ IB,
                                                const c64* __restrict__ tw){
    __shared__ double re[4096]; __shared__ double im[4096];
    const int t = threadIdx.x, blk = blockIdx.x;
    const size_t base = (size_t)(blk >> 6) * IMGE + (size_t)(blk & 63) * 8;
    col_load(t2, base, re, im);
    r8_dit<true>(re, im, tw);
    __syncthreads();
    const double sc = 1.0/512.0;
    #pragma unroll
    for (int it = 0; it < 16; ++it){
        int idx = it*256 + t; int ln = idx & 7, e = idx >> 3;
        size_t addr = base + ln + (size_t)e*512;
        int p = SW(ln, e);
        double br_ = re[p]*sc, bi_ = im[p]*sc;    // IB
        IB[addr] = make_double2(br_, bi_);
        float2 h = H[addr];
        double qr, qi;
        if (WONE){ qr = (double)h.x; qi = (double)h.y; }
        else { c64 w = Wa[addr]; qr = (double)h.x*w.x - (double)h.y*w.y; qi = (double)h.x*w.y + (double)h.y*w.x; }
        re[p] = qr - br_;
        im[p] = qi - bi_;
    }
    r8_dif<false>(re, im, tw);
    __syncthreads();
    #pragma unroll
    for (int it = 0; it < 16; ++it){
        int idx = it*256 + t; int ln = idx & 7, e = idx >> 3;
        int p = SW(ln, rev8(e));
        t2[base + ln + (size_t)e*512] = make_double2(re[p], im[p]);
    }
}

// ---------------- k_colX: colI -> X = inp1*(|inp1|>LAM) -> colF(X) ----------------
__global__ __launch_bounds__(256) void k_colX(c64* __restrict__ t2,
                                              const c64* __restrict__ tw){
    __shared__ double re[4096]; __shared__ double im[4096];
    const int t = threadIdx.x, blk = blockIdx.x;
    const size_t base = (size_t)(blk >> 6) * IMGE + (size_t)(blk & 63) * 8;
    col_load(t2, base, re, im);
    r8_dit<true>(re, im, tw);
    __syncthreads();
    const double sc = 1.0/512.0;
    #pragma unroll
    for (int it = 0; it < 16; ++it){
        int idx = it*256 + t;
        int p = SW(idx & 7, idx >> 3);
        double vr = re[p]*sc, vi = im[p]*sc;      // inp1
        double m = sqrt(vr*vr + vi*vi);
        bool keep = m > LAMD;
        re[p] = keep ? vr : 0.0;
        im[p] = keep ? vi : 0.0;
    }
    r8_dif<false>(re, im, tw);
    __syncthreads();
    #pragma unroll
    for (int it = 0; it < 16; ++it){
        int idx = it*256 + t; int ln = idx & 7, e = idx >> 3;
        int p = SW(ln, rev8(e));
        t2[base + ln + (size_t)e*512] = make_double2(re[p], im[p]);
    }
}

// ---------------- final masked B -> d_out second half ----------------
__global__ __launch_bounds__(256) void k_outB(const c64* __restrict__ B,
                                              const unsigned int* __restrict__ keys,
                                              const SelState* __restrict__ st,
                                              float2* __restrict__ outB){
    int i = blockIdx.x*256 + threadIdx.x;
    c64 v = B[i];
    if (keys[i] < st->thrkey) v = make_double2(0.0, 0.0);
    outB[i] = make_float2((float)v.x, (float)v.y);
}

// ---------------- radix select: filtered histogram + parallel scan ----------------
__global__ __launch_bounds__(256) void k_hist(const unsigned int* __restrict__ keys,
                                              unsigned int* __restrict__ hist,
                                              const SelState* __restrict__ st,
                                              int shiftHi, int shift, int dbits){
    __shared__ unsigned int lh[2048];
    int t = threadIdx.x;
    int nd = 1 << dbits;
    for (int b = t; b < nd; b += 256) lh[b] = 0u;
    __syncthreads();
    unsigned known = st->known;
    unsigned msk = (unsigned)((1u << dbits) - 1u);
    for (int i = blockIdx.x*256 + t; i < TOT; i += gridDim.x*256){
        unsigned k = keys[i];
        bool ok = (shiftHi >= 32);
        if (!ok) ok = ((k >> shiftHi) == known);
        if (ok) atomicAdd(&lh[(k >> shift) & msk], 1u);
    }
    __syncthreads();
    for (int b = t; b < nd; b += 256){
        unsigned v = lh[b];
        if (v) atomicAdd(&hist[b], v);
    }
}

// mode: 2=first pass (rank=BETA, known=0), 0=middle, 1=last (writes thrkey).
__global__ __launch_bounds__(256) void k_scan(unsigned int* __restrict__ hist,
                                              SelState* __restrict__ st,
                                              int dbits, int mode){
    __shared__ unsigned int s[256];
    const int t = threadIdx.x;
    const int nd = 1 << dbits;
    const int per = nd >> 8;
    unsigned c[8];
    unsigned local = 0u;
    const int b0 = t * per;
    #pragma unroll
    for (int j = 0; j < 8; ++j){
        unsigned v = 0u;
        if (j < per){ v = hist[b0 + j]; hist[b0 + j] = 0u; }
        c[j] = v; local += v;
    }
    unsigned rank = (mode == 2) ? (unsigned)BETA_K : st->rank;
    s[t] = local;
    __syncthreads();
    #pragma unroll
    for (int off = 1; off < 256; off <<= 1){
        unsigned add = (t + off < 256) ? s[t + off] : 0u;
        __syncthreads();
        s[t] += add;
        __syncthreads();
    }
    unsigned stot   = s[t];
    unsigned sAfter = (t < 255) ? s[t + 1] : 0u;
    if (sAfter < rank && stot >= rank){
        unsigned cum = sAfter;
        int j = per - 1;
        #pragma unroll
        for (int k = 7; k >= 0; --k){
            if (k > per - 1) continue;
            j = k;
            if (cum + c[k] >= rank) break;
            cum += c[k];
        }
        st->rank = rank - cum;
        unsigned kn = (mode == 2) ? 0u : st->known;
        unsigned nk = (kn << dbits) | (unsigned)(b0 + j);
        st->known = nk;
        if (mode == 1) st->thrkey = nk;
    }
}

// ---------------- orchestration ----------------
// ws: t2 32M | B 32M | IB 32M | keys 8M | T 4M | tw 8K | hist 8K | st   (~108 MB)
// d_out (32 MiB) hosts W as f64 during the loop; final kernels overwrite with f32 outputs.
extern "C" void kernel_launch(void* const* d_in, const int* in_sizes, int n_in,
                              void* d_out, int out_size, void* d_ws, size_t ws_size,
                              hipStream_t stream){
    (void)in_sizes; (void)n_in; (void)out_size; (void)ws_size;
    const float2* H = (const float2*)d_in[0];
    const float*  Q = (const float*)d_in[1];
    const float*  zp = (const float*)d_in[2];

    char* ws = (char*)d_ws;
    const size_t A = (size_t)TOT * 16;   // 32 MiB
    c64* t2 = (c64*)(ws);
    c64* B  = (c64*)(ws + A);
    c64* IB = (c64*)(ws + 2*A);
    unsigned int* keys = (unsigned int*)(ws + 3*A);
    c64* T  = (c64*)(ws + 3*A + (size_t)TOT*4);
    c64* tw = (c64*)(ws + 3*A + (size_t)TOT*4 + (size_t)IMGE*16);
    unsigned int* hist = (unsigned int*)((char*)tw + 512*16);
    SelState* st = (SelState*)((char*)hist + 8192);

    c64* Wd = (c64*)d_out;                   // f64 W (32 MiB) during loop
    float2* outW = (float2*)d_out;           // final outputs
    float2* outB = ((float2*)d_out) + TOT;

    hipMemsetAsync(hist, 0, 2048*sizeof(unsigned int), stream);
    k_init<<<IMGE/256, 256, 0, stream>>>(Q, zp, T, tw);

    auto sel = [&](){
        k_hist<<<1024,256,0,stream>>>(keys, hist, st, 64, 21, 11);
        k_scan<<<1,256,0,stream>>>(hist, st, 11, 2);
        k_hist<<<1024,256,0,stream>>>(keys, hist, st, 21, 10, 11);
        k_scan<<<1,256,0,stream>>>(hist, st, 11, 0);
        k_hist<<<1024,256,0,stream>>>(keys, hist, st, 10, 0, 10);
        k_scan<<<1,256,0,stream>>>(hist, st, 10, 1);
    };

    // ---- iteration 1 (X=0 -> convXT=0, B0=fft2(ones) delta -> W=1, R=H) ----
    k_colF<<<512,256,0,stream>>>(H, t2, tw);
    k_rowB<<<512,256,0,stream>>>(t2, B, keys, tw);
    sel();
    k_rowMI<<<512,256,0,stream>>>(B, keys, st, t2, tw);
    k_colSIB<true><<<512,256,0,stream>>>(t2, H, Wd, IB, tw);
    k_rowT<true><<<512,256,0,stream>>>(t2, T, tw);
    k_colX<<<512,256,0,stream>>>(t2, tw);

    // ---- iterations 2..5 ----
    for (int iter = 2; iter <= 5; ++iter){
        k_rowT<false><<<512,256,0,stream>>>(t2, T, tw);
        k_colWR<false><<<512,256,0,stream>>>(t2, H, IB, (void*)Wd, tw);
        k_rowB<<<512,256,0,stream>>>(t2, B, keys, tw);
        sel();
        k_rowMI<<<512,256,0,stream>>>(B, keys, st, t2, tw);
        k_colSIB<false><<<512,256,0,stream>>>(t2, H, Wd, IB, tw);
        k_rowT<true><<<512,256,0,stream>>>(t2, T, tw);
        k_colX<<<512,256,0,stream>>>(t2, tw);
    }

    // ---- iteration 6: only W and masked B needed ----
    k_rowT<false><<<512,256,0,stream>>>(t2, T, tw);
    k_colWR<true><<<512,256,0,stream>>>(t2, H, IB, (void*)outW, tw);
    k_rowB<<<512,256,0,stream>>>(t2, B, keys, tw);
    sel();
    k_outB<<<TOT/256,256,0,stream>>>(B, keys, st, outB);
}

// Round 5
// 1031.063 us; speedup vs baseline: 3.3782x; 1.0768x over previous
//
#include <hip/hip_runtime.h>
#include <math.h>

// Problem constants
#define NIMG 8
#define MDIM 512
#define IMGE (MDIM*MDIM)        // 262144 per image
#define TOT  (NIMG*IMGE)        // 2097152 complex elements
#define BETA_K 4096
#define LAMD 0.1

typedef double2 c64;

struct SelState { unsigned int known; unsigned int rank; unsigned int thrkey; };

// ---------------- LDS addressing: 8 lines x 512 f64(x2 arrays) ----------------
// XOR swizzle into the bank-quad bits (1..3), line-dependent. Verified at the
// bank-BW floor for stage strides 1/8/64 (b128 & b64) and the digit-reversed
// col load/store pattern. Preserves pair-contiguity (bit0 untouched) so
// 8-consecutive-f64 groups still merge into ds_*_b128.
__device__ __forceinline__ int LPOS(int ln, int q){
    return (ln << 9) + (q ^ ((((q >> 4) ^ (2 * ln)) & 7) << 1));
}
__device__ __forceinline__ int rev8(int n){   // base-8 digit reversal of 9-bit index
    return ((n & 7) << 6) | (n & 56) | (n >> 6);
}
__device__ __forceinline__ int rde(int w, int k){ // rev8(8w+k)
    return 64*k + 8*(w & 7) + (w >> 3);
}

// ---------------- 8-point DFT in registers. INV=true: conjugate (inverse) ----------------
template<bool INV>
__device__ __forceinline__ void dft8(double* xr, double* xi){
    const double C = 0.70710678118654752440;
    double t0r=xr[0]+xr[4], t0i=xi[0]+xi[4];
    double t1r=xr[0]-xr[4], t1i=xi[0]-xi[4];
    double t2r=xr[2]+xr[6], t2i=xi[2]+xi[6];
    double t3r=xr[2]-xr[6], t3i=xi[2]-xi[6];
    double m3r = INV ? -t3i : t3i;
    double m3i = INV ?  t3r : -t3r;
    double E0r=t0r+t2r, E0i=t0i+t2i;
    double E2r=t0r-t2r, E2i=t0i-t2i;
    double E1r=t1r+m3r, E1i=t1i+m3i;
    double E3r=t1r-m3r, E3i=t1i-m3i;
    double u0r=xr[1]+xr[5], u0i=xi[1]+xi[5];
    double u1r=xr[1]-xr[5], u1i=xi[1]-xi[5];
    double u2r=xr[3]+xr[7], u2i=xi[3]+xi[7];
    double u3r=xr[3]-xr[7], u3i=xi[3]-xi[7];
    double n3r = INV ? -u3i : u3i;
    double n3i = INV ?  u3r : -u3r;
    double O0r=u0r+u2r, O0i=u0i+u2i;
    double O2r=u0r-u2r, O2i=u0i-u2i;
    double O1r=u1r+n3r, O1i=u1i+n3i;
    double O3r=u1r-n3r, O3i=u1i-n3i;
    double W1r = INV ? C*(O1r - O1i) : C*(O1r + O1i);
    double W1i = INV ? C*(O1r + O1i) : C*(O1i - O1r);
    double W2r = INV ? -O2i : O2i;
    double W2i = INV ?  O2r : -O2r;
    double W3r = INV ? -C*(O3r + O3i) : C*(O3i - O3r);
    double W3i = INV ?  C*(O3r - O3i) : -C*(O3r + O3i);
    xr[0]=E0r+O0r; xi[0]=E0i+O0i;  xr[4]=E0r-O0r; xi[4]=E0i-O0i;
    xr[1]=E1r+W1r; xi[1]=E1i+W1i;  xr[5]=E1r-W1r; xi[5]=E1i-W1i;
    xr[2]=E2r+W2r; xi[2]=E2i+W2i;  xr[6]=E2r-W2r; xi[6]=E2i-W2i;
    xr[3]=E3r+W3r; xi[3]=E3i+W3i;  xr[7]=E3r-W3r; xi[7]=E3i-W3i;
}

// ================= ROW-path FFT helpers (register ends) =================
// dit_from_regs: entry: ar[h][k] = input element rev8(8w+k) of line l0+4h.
//                exit:  ar[h][k] = natural-order output element (w + 64k).
template<bool INV>
__device__ __forceinline__ void dit_from_regs(double (&ar)[2][8], double (&ai)[2][8],
                                              double* re, double* im, const c64* __restrict__ tw){
    const int t=threadIdx.x, w=t&63, l0=t>>6;
    #pragma unroll
    for (int h=0;h<2;++h){
        dft8<INV>(ar[h], ai[h]);
        const int ln=l0+4*h;
        #pragma unroll
        for (int k=0;k<8;++k){ int p=LPOS(ln,8*w+k); re[p]=ar[h][k]; im[p]=ai[h][k]; }
    }
    __syncthreads();
    {   // stage 1: groups 64g+j+8k, twiddle tw[8jk]
        const int g=w>>3, j=w&7;
        double wr[8], wi[8];
        #pragma unroll
        for (int k=1;k<8;++k){ c64 tv=tw[8*j*k]; wr[k]=tv.x; wi[k]=INV?-tv.y:tv.y; }
        #pragma unroll
        for (int h=0;h<2;++h){
            const int ln=l0+4*h;
            double xr[8], xi[8];
            #pragma unroll
            for (int k=0;k<8;++k){ int p=LPOS(ln,64*g+j+8*k); double a=re[p],b=im[p];
                if(k==0){xr[0]=a; xi[0]=b;} else {xr[k]=a*wr[k]-b*wi[k]; xi[k]=a*wi[k]+b*wr[k];} }
            dft8<INV>(xr,xi);
            #pragma unroll
            for (int k=0;k<8;++k){ int p=LPOS(ln,64*g+j+8*k); re[p]=xr[k]; im[p]=xi[k]; }
        }
    }
    __syncthreads();
    {   // stage 2 -> regs: groups j+64k, twiddle tw[jk]
        const int j=w;
        double wr[8], wi[8];
        #pragma unroll
        for (int k=1;k<8;++k){ c64 tv=tw[j*k]; wr[k]=tv.x; wi[k]=INV?-tv.y:tv.y; }
        #pragma unroll
        for (int h=0;h<2;++h){
            const int ln=l0+4*h;
            #pragma unroll
            for (int k=0;k<8;++k){ int p=LPOS(ln,j+64*k); double a=re[p],b=im[p];
                if(k==0){ar[h][0]=a; ai[h][0]=b;} else {ar[h][k]=a*wr[k]-b*wi[k]; ai[h][k]=a*wi[k]+b*wr[k];} }
            dft8<INV>(ar[h], ai[h]);
        }
    }
}

// dif_to_regs: entry: ar[h][k] = natural element (w + 64k) of line l0+4h.
//              exit:  ar[h][k] = output element rev8(8w+k) = rde(w,k).
// NOTE: stage-A writes hit only this thread's own stage-2-read positions, so
// no barrier is needed between a preceding dit_from_regs and this call.
template<bool INV>
__device__ __forceinline__ void dif_to_regs(double (&ar)[2][8], double (&ai)[2][8],
                                            double* re, double* im, const c64* __restrict__ tw){
    const int t=threadIdx.x, w=t&63, l0=t>>6;
    {   // stage A (from regs): dft8, post-twiddle tw[w*k], write at j+64k
        const int j=w;
        double wr[8], wi[8];
        #pragma unroll
        for (int k=1;k<8;++k){ c64 tv=tw[j*k]; wr[k]=tv.x; wi[k]=INV?-tv.y:tv.y; }
        #pragma unroll
        for (int h=0;h<2;++h){
            dft8<INV>(ar[h], ai[h]);
            const int ln=l0+4*h;
            #pragma unroll
            for (int k=0;k<8;++k){
                int p=LPOS(ln,j+64*k);
                if(k==0){ re[p]=ar[h][0]; im[p]=ai[h][0]; }
                else { re[p]=ar[h][k]*wr[k]-ai[h][k]*wi[k]; im[p]=ar[h][k]*wi[k]+ai[h][k]*wr[k]; }
            }
        }
    }
    __syncthreads();
    {   // stage B: groups 64g+j+8k, post-twiddle tw[8jk]
        const int g=w>>3, j=w&7;
        double wr[8], wi[8];
        #pragma unroll
        for (int k=1;k<8;++k){ c64 tv=tw[8*j*k]; wr[k]=tv.x; wi[k]=INV?-tv.y:tv.y; }
        #pragma unroll
        for (int h=0;h<2;++h){
            const int ln=l0+4*h;
            double xr[8], xi[8];
            #pragma unroll
            for (int k=0;k<8;++k){ int p=LPOS(ln,64*g+j+8*k); xr[k]=re[p]; xi[k]=im[p]; }
            dft8<INV>(xr,xi);
            #pragma unroll
            for (int k=0;k<8;++k){
                int p=LPOS(ln,64*g+j+8*k);
                if(k==0){ re[p]=xr[0]; im[p]=xi[0]; }
                else { re[p]=xr[k]*wr[k]-xi[k]*wi[k]; im[p]=xr[k]*wi[k]+xi[k]*wr[k]; }
            }
        }
    }
    __syncthreads();
    // stage C -> regs (no twiddle)
    #pragma unroll
    for (int h=0;h<2;++h){
        const int ln=l0+4*h;
        #pragma unroll
        for (int k=0;k<8;++k){ int p=LPOS(ln,8*w+k); ar[h][k]=re[p]; ai[h][k]=im[p]; }
        dft8<INV>(ar[h], ai[h]);
    }
}

// ================= COL-path FFT (full-LDS, round-4 structure) =================
template<bool INV>
__device__ void r8_dit(double* re, double* im, const c64* __restrict__ tw){
    const int t = threadIdx.x;
    const int w = t & 63;
    const int l0 = t >> 6;
    __syncthreads();
    #pragma unroll
    for (int h = 0; h < 2; ++h){
        const int ln = l0 + 4*h;
        double xr[8], xi[8];
        #pragma unroll
        for (int k = 0; k < 8; ++k){ int p = LPOS(ln, 8*w + k); xr[k]=re[p]; xi[k]=im[p]; }
        dft8<INV>(xr, xi);
        #pragma unroll
        for (int k = 0; k < 8; ++k){ int p = LPOS(ln, 8*w + k); re[p]=xr[k]; im[p]=xi[k]; }
    }
    {
        const int g = w >> 3, j = w & 7;
        double wr[8], wi[8];
        #pragma unroll
        for (int k = 1; k < 8; ++k){ c64 tv = tw[8*j*k]; wr[k]=tv.x; wi[k]= INV ? -tv.y : tv.y; }
        __syncthreads();
        #pragma unroll
        for (int h = 0; h < 2; ++h){
            const int ln = l0 + 4*h;
            double xr[8], xi[8];
            #pragma unroll
            for (int k = 0; k < 8; ++k){
                int p = LPOS(ln, 64*g + j + 8*k); double ar=re[p], ai=im[p];
                if (k == 0){ xr[0]=ar; xi[0]=ai; }
                else { xr[k]=ar*wr[k]-ai*wi[k]; xi[k]=ar*wi[k]+ai*wr[k]; }
            }
            dft8<INV>(xr, xi);
            #pragma unroll
            for (int k = 0; k < 8; ++k){ int p = LPOS(ln, 64*g + j + 8*k); re[p]=xr[k]; im[p]=xi[k]; }
        }
    }
    {
        const int j = w;
        double wr[8], wi[8];
        #pragma unroll
        for (int k = 1; k < 8; ++k){ c64 tv = tw[j*k]; wr[k]=tv.x; wi[k]= INV ? -tv.y : tv.y; }
        __syncthreads();
        #pragma unroll
        for (int h = 0; h < 2; ++h){
            const int ln = l0 + 4*h;
            double xr[8], xi[8];
            #pragma unroll
            for (int k = 0; k < 8; ++k){
                int p = LPOS(ln, j + 64*k); double ar=re[p], ai=im[p];
                if (k == 0){ xr[0]=ar; xi[0]=ai; }
                else { xr[k]=ar*wr[k]-ai*wi[k]; xi[k]=ar*wi[k]+ai*wr[k]; }
            }
            dft8<INV>(xr, xi);
            #pragma unroll
            for (int k = 0; k < 8; ++k){ int p = LPOS(ln, j + 64*k); re[p]=xr[k]; im[p]=xi[k]; }
        }
    }
}

template<bool INV>
__device__ void r8_dif(double* re, double* im, const c64* __restrict__ tw){
    const int t = threadIdx.x;
    const int w = t & 63;
    const int l0 = t >> 6;
    {
        const int j = w;
        double wr[8], wi[8];
        #pragma unroll
        for (int k = 1; k < 8; ++k){ c64 tv = tw[j*k]; wr[k]=tv.x; wi[k]= INV ? -tv.y : tv.y; }
        __syncthreads();
        #pragma unroll
        for (int h = 0; h < 2; ++h){
            const int ln = l0 + 4*h;
            double xr[8], xi[8];
            #pragma unroll
            for (int k = 0; k < 8; ++k){ int p = LPOS(ln, j + 64*k); xr[k]=re[p]; xi[k]=im[p]; }
            dft8<INV>(xr, xi);
            #pragma unroll
            for (int k = 0; k < 8; ++k){
                int p = LPOS(ln, j + 64*k);
                if (k == 0){ re[p]=xr[0]; im[p]=xi[0]; }
                else { re[p]=xr[k]*wr[k]-xi[k]*wi[k]; im[p]=xr[k]*wi[k]+xi[k]*wr[k]; }
            }
        }
    }
    {
        const int g = w >> 3, j = w & 7;
        double wr[8], wi[8];
        #pragma unroll
        for (int k = 1; k < 8; ++k){ c64 tv = tw[8*j*k]; wr[k]=tv.x; wi[k]= INV ? -tv.y : tv.y; }
        __syncthreads();
        #pragma unroll
        for (int h = 0; h < 2; ++h){
            const int ln = l0 + 4*h;
            double xr[8], xi[8];
            #pragma unroll
            for (int k = 0; k < 8; ++k){ int p = LPOS(ln, 64*g + j + 8*k); xr[k]=re[p]; xi[k]=im[p]; }
            dft8<INV>(xr, xi);
            #pragma unroll
            for (int k = 0; k < 8; ++k){
                int p = LPOS(ln, 64*g + j + 8*k);
                if (k == 0){ re[p]=xr[0]; im[p]=xi[0]; }
                else { re[p]=xr[k]*wr[k]-xi[k]*wi[k]; im[p]=xr[k]*wi[k]+xi[k]*wr[k]; }
            }
        }
    }
    __syncthreads();
    #pragma unroll
    for (int h = 0; h < 2; ++h){
        const int ln = l0 + 4*h;
        double xr[8], xi[8];
        #pragma unroll
        for (int k = 0; k < 8; ++k){ int p = LPOS(ln, 8*w + k); xr[k]=re[p]; xi[k]=im[p]; }
        dft8<INV>(xr, xi);
        #pragma unroll
        for (int k = 0; k < 8; ++k){ int p = LPOS(ln, 8*w + k); re[p]=xr[k]; im[p]=xi[k]; }
    }
}

__device__ __forceinline__ void col_load64(const c64* __restrict__ src, size_t base,
                                           double* re, double* im){
    const int t = threadIdx.x;
    #pragma unroll
    for (int it = 0; it < 16; ++it){
        int idx = it*256 + t; int ln = idx & 7, e = idx >> 3;
        c64 v = src[base + ln + (size_t)e*512];
        int p = LPOS(ln, rev8(e));
        re[p] = v.x; im[p] = v.y;
    }
}

// ---------------- init ----------------
__global__ __launch_bounds__(256) void k_init(const float* __restrict__ Q,
                                              const float* __restrict__ zp,
                                              c64* __restrict__ T,
                                              c64* __restrict__ tw){
    int i = blockIdx.x*256 + threadIdx.x;
    if (i < IMGE){
        double a = ((double)zp[0] / 6.37e-07) * (double)Q[i];
        T[i] = make_double2(cos(a), sin(a));
    }
    if (i < 512){
        double a = -6.283185307179586476925286766559 * ((double)i / 512.0);
        tw[i] = make_double2(cos(a), sin(a));
    }
}

// ---------------- k_colF: forward col FFT of H (f32) -> t2 ----------------
__global__ __launch_bounds__(256,2) void k_colF(const float2* __restrict__ H,
                                                c64* __restrict__ t2,
                                                const c64* __restrict__ tw){
    __shared__ double re[4096]; __shared__ double im[4096];
    const int t = threadIdx.x, blk = blockIdx.x;
    const size_t base = (size_t)(blk >> 6) * IMGE + (size_t)(blk & 63) * 8;
    #pragma unroll
    for (int it = 0; it < 16; ++it){
        int idx = it*256 + t; int ln = idx & 7, e = idx >> 3;
        float2 v = H[base + ln + (size_t)e*512];
        int p = LPOS(ln, rev8(e));
        re[p] = (double)v.x; im[p] = (double)v.y;
    }
    r8_dit<false>(re, im, tw);
    __syncthreads();
    #pragma unroll
    for (int it = 0; it < 16; ++it){
        int idx = it*256 + t; int ln = idx & 7, e = idx >> 3;
        int p = LPOS(ln, e);
        t2[base + ln + (size_t)e*512] = make_double2(re[p], im[p]);
    }
}

// ---------------- k_rowT: rowF -> *T (or conj) -> rowI (x1/512), reg-ended ----------------
template<bool CONJ>
__global__ __launch_bounds__(256,2) void k_rowT(c64* __restrict__ t2,
                                                const c64* __restrict__ T,
                                                const c64* __restrict__ tw){
    __shared__ double re[4096]; __shared__ double im[4096];
    const int t = threadIdx.x, blk = blockIdx.x;
    const int w = t & 63, l0 = t >> 6;
    const size_t base = (size_t)blk * 4096;
    double ar[2][8], ai[2][8];
    #pragma unroll
    for (int h=0;h<2;++h){ const int ln=l0+4*h;
        #pragma unroll
        for (int k=0;k<8;++k){ c64 v = t2[base + ln*512 + rde(w,k)]; ar[h][k]=v.x; ai[h][k]=v.y; } }
    dit_from_regs<false>(ar, ai, re, im, tw);
    // elementwise in regs: element index e = w + 64k, image row u = (blk*8+ln)&511
    #pragma unroll
    for (int h=0;h<2;++h){
        const int ln=l0+4*h;
        const int u = ((blk & 63) * 8 + ln) & 511;
        #pragma unroll
        for (int k=0;k<8;++k){
            c64 tv = T[u*512 + (w + 64*k)];
            double ti = CONJ ? -tv.y : tv.y;
            double xr = ar[h][k], xi = ai[h][k];
            ar[h][k] = xr*tv.x - xi*ti;
            ai[h][k] = xr*ti + xi*tv.x;
        }
    }
    dif_to_regs<true>(ar, ai, re, im, tw);
    const double sc = 1.0/512.0;
    #pragma unroll
    for (int h=0;h<2;++h){ const int ln=l0+4*h;
        #pragma unroll
        for (int k=0;k<8;++k)
            t2[base + ln*512 + rde(w,k)] = make_double2(ar[h][k]*sc, ai[h][k]*sc); }
}

// ---------------- k_rowB: rowF -> B + keys + hist pass-1 (fused) ----------------
__global__ __launch_bounds__(256,2) void k_rowB(const c64* __restrict__ t2,
                                                c64* __restrict__ B,
                                                unsigned int* __restrict__ keys,
                                                unsigned int* __restrict__ hist,
                                                const c64* __restrict__ tw){
    __shared__ double re[4096]; __shared__ double im[4096];
    const int t = threadIdx.x, blk = blockIdx.x;
    const int w = t & 63, l0 = t >> 6;
    const size_t base = (size_t)blk * 4096;
    double ar[2][8], ai[2][8];
    #pragma unroll
    for (int h=0;h<2;++h){ const int ln=l0+4*h;
        #pragma unroll
        for (int k=0;k<8;++k){ c64 v = t2[base + ln*512 + rde(w,k)]; ar[h][k]=v.x; ai[h][k]=v.y; } }
    dit_from_regs<false>(ar, ai, re, im, tw);
    __syncthreads();                       // all stage-2 LDS reads done -> reuse re as hist
    unsigned int* lh = reinterpret_cast<unsigned int*>(re);
    for (int b = t; b < 2048; b += 256) lh[b] = 0u;
    __syncthreads();
    #pragma unroll
    for (int h=0;h<2;++h){
        const int ln=l0+4*h;
        #pragma unroll
        for (int k=0;k<8;++k){
            double xr = ar[h][k], xi = ai[h][k];
            size_t addr = base + ln*512 + (w + 64*k);
            B[addr] = make_double2(xr, xi);
            unsigned int key = __float_as_uint((float)sqrt(xr*xr + xi*xi));
            keys[addr] = key;
            atomicAdd(&lh[key >> 21], 1u);
        }
    }
    __syncthreads();
    for (int b = t; b < 2048; b += 256){
        unsigned int v = lh[b];
        if (v) atomicAdd(&hist[b], v);
    }
}

// ---------------- k_rowMI: mask(B) -> rowI (x1/512), reg-ended ----------------
__global__ __launch_bounds__(256,2) void k_rowMI(const c64* __restrict__ B,
                                                 const unsigned int* __restrict__ keys,
                                                 const SelState* __restrict__ st,
                                                 c64* __restrict__ t2,
                                                 const c64* __restrict__ tw){
    __shared__ double re[4096]; __shared__ double im[4096];
    const int t = threadIdx.x, blk = blockIdx.x;
    const int w = t & 63, l0 = t >> 6;
    const size_t base = (size_t)blk * 4096;
    const unsigned int thr = st->thrkey;
    double ar[2][8], ai[2][8];
    #pragma unroll
    for (int h=0;h<2;++h){ const int ln=l0+4*h;
        #pragma unroll
        for (int k=0;k<8;++k){
            size_t addr = base + ln*512 + (w + 64*k);
            c64 v = B[addr];
            if (keys[addr] < thr) v = make_double2(0.0, 0.0);
            ar[h][k]=v.x; ai[h][k]=v.y;
        } }
    dif_to_regs<true>(ar, ai, re, im, tw);
    const double sc = 1.0/512.0;
    #pragma unroll
    for (int h=0;h<2;++h){ const int ln=l0+4*h;
        #pragma unroll
        for (int k=0;k<8;++k)
            t2[base + ln*512 + rde(w,k)] = make_double2(ar[h][k]*sc, ai[h][k]*sc); }
}

// ---------------- k_colWR: colI(convXT) -> W,R -> colF(R) ----------------
template<bool FINAL>
__global__ __launch_bounds__(256,2) void k_colWR(c64* __restrict__ t2,
                                                 const float2* __restrict__ H,
                                                 const c64* __restrict__ IB,
                                                 void* __restrict__ Wout,
                                                 const c64* __restrict__ tw){
    __shared__ double re[4096]; __shared__ double im[4096];
    const int t = threadIdx.x, blk = blockIdx.x;
    const size_t base = (size_t)(blk >> 6) * IMGE + (size_t)(blk & 63) * 8;
    col_load64(t2, base, re, im);
    r8_dit<true>(re, im, tw);
    __syncthreads();
    const double sc = 1.0/512.0;
    #pragma unroll
    for (int it = 0; it < 16; ++it){
        int idx = it*256 + t; int ln = idx & 7, e = idx >> 3;
        size_t addr = base + ln + (size_t)e*512;
        int p = LPOS(ln, e);
        double cr = re[p]*sc, ci = im[p]*sc;      // convXT
        c64 b = IB[addr];
        double sx = cr + b.x, sy = ci + b.y;
        double m = sqrt(sx*sx + sy*sy);
        double d = (m == 0.0) ? 1.0 : m;
        double wx = sx/d, wy = sy/d;
        if (FINAL) ((float2*)Wout)[addr] = make_float2((float)wx, (float)wy);
        else       ((c64*)Wout)[addr]    = make_double2(wx, wy);
        float2 h = H[addr];
        re[p] = (double)h.x*wx - (double)h.y*wy - cr;   // R = H*W - convXT
        im[p] = (double)h.x*wy + (double)h.y*wx - ci;
    }
    r8_dif<false>(re, im, tw);
    __syncthreads();
    #pragma unroll
    for (int it = 0; it < 16; ++it){
        int idx = it*256 + t; int ln = idx & 7, e = idx >> 3;
        int p = LPOS(ln, rev8(e));
        t2[base + ln + (size_t)e*512] = make_double2(re[p], im[p]);
    }
}

// ---------------- k_colSIB: colI -> IB store, S = Qc - IB -> colF(S) ----------------
template<bool WONE>
__global__ __launch_bounds__(256,2) void k_colSIB(c64* __restrict__ t2,
                                                  const float2* __restrict__ H,
                                                  const c64* __restrict__ Wa,
                                                  c64* __restrict__ IB,
                                                  const c64* __restrict__ tw){
    __shared__ double re[4096]; __shared__ double im[4096];
    const int t = threadIdx.x, blk = blockIdx.x;
    const size_t base = (size_t)(blk >> 6) * IMGE + (size_t)(blk & 63) * 8;
    col_load64(t2, base, re, im);
    r8_dit<true>(re, im, tw);
    __syncthreads();
    const double sc = 1.0/512.0;
    #pragma unroll
    for (int it = 0; it < 16; ++it){
        int idx = it*256 + t; int ln = idx & 7, e = idx >> 3;
        size_t addr = base + ln + (size_t)e*512;
        int p = LPOS(ln, e);
        double br_ = re[p]*sc, bi_ = im[p]*sc;    // IB
        IB[addr] = make_double2(br_, bi_);
        float2 h = H[addr];
        double qr, qi;
        if (WONE){ qr = (double)h.x; qi = (double)h.y; }
        else { c64 w = Wa[addr]; qr = (double)h.x*w.x - (double)h.y*w.y; qi = (double)h.x*w.y + (double)h.y*w.x; }
        re[p] = qr - br_;
        im[p] = qi - bi_;
    }
    r8_dif<false>(re, im, tw);
    __syncthreads();
    #pragma unroll
    for (int it = 0; it < 16; ++it){
        int idx = it*256 + t; int ln = idx & 7, e = idx >> 3;
        int p = LPOS(ln, rev8(e));
        t2[base + ln + (size_t)e*512] = make_double2(re[p], im[p]);
    }
}

// ---------------- k_colX: colI -> X = inp1*(|inp1|>LAM) -> colF(X) ----------------
__global__ __launch_bounds__(256,2) void k_colX(c64* __restrict__ t2,
                                                const c64* __restrict__ tw){
    __shared__ double re[4096]; __shared__ double im[4096];
    const int t = threadIdx.x, blk = blockIdx.x;
    const size_t base = (size_t)(blk >> 6) * IMGE + (size_t)(blk & 63) * 8;
    col_load64(t2, base, re, im);
    r8_dit<true>(re, im, tw);
    __syncthreads();
    const double sc = 1.0/512.0;
    #pragma unroll
    for (int it = 0; it < 16; ++it){
        int idx = it*256 + t;
        int p = LPOS(idx & 7, idx >> 3);
        double vr = re[p]*sc, vi = im[p]*sc;      // inp1
        double m = sqrt(vr*vr + vi*vi);
        bool keep = m > LAMD;
        re[p] = keep ? vr : 0.0;
        im[p] = keep ? vi : 0.0;
    }
    r8_dif<false>(re, im, tw);
    __syncthreads();
    #pragma unroll
    for (int it = 0; it < 16; ++it){
        int idx = it*256 + t; int ln = idx & 7, e = idx >> 3;
        int p = LPOS(ln, rev8(e));
        t2[base + ln + (size_t)e*512] = make_double2(re[p], im[p]);
    }
}

// ---------------- final masked B -> d_out second half ----------------
__global__ __launch_bounds__(256) void k_outB(const c64* __restrict__ B,
                                              const unsigned int* __restrict__ keys,
                                              const SelState* __restrict__ st,
                                              float2* __restrict__ outB){
    int i = blockIdx.x*256 + threadIdx.x;
    c64 v = B[i];
    if (keys[i] < st->thrkey) v = make_double2(0.0, 0.0);
    outB[i] = make_float2((float)v.x, (float)v.y);
}

// ---------------- radix select: filtered histogram + parallel scan ----------------
__global__ __launch_bounds__(256) void k_hist(const unsigned int* __restrict__ keys,
                                              unsigned int* __restrict__ hist,
                                              const SelState* __restrict__ st,
                                              int shiftHi, int shift, int dbits){
    __shared__ unsigned int lh[2048];
    int t = threadIdx.x;
    int nd = 1 << dbits;
    for (int b = t; b < nd; b += 256) lh[b] = 0u;
    __syncthreads();
    unsigned known = st->known;
    unsigned msk = (unsigned)((1u << dbits) - 1u);
    for (int i = blockIdx.x*256 + t; i < TOT; i += gridDim.x*256){
        unsigned k = keys[i];
        if ((k >> shiftHi) == known) atomicAdd(&lh[(k >> shift) & msk], 1u);
    }
    __syncthreads();
    for (int b = t; b < nd; b += 256){
        unsigned v = lh[b];
        if (v) atomicAdd(&hist[b], v);
    }
}

// mode: 2=first pass (rank=BETA, known=0), 0=middle, 1=last (writes thrkey).
__global__ __launch_bounds__(256) void k_scan(unsigned int* __restrict__ hist,
                                              SelState* __restrict__ st,
                                              int dbits, int mode){
    __shared__ unsigned int s[256];
    const int t = threadIdx.x;
    const int nd = 1 << dbits;
    const int per = nd >> 8;
    unsigned c[8];
    unsigned local = 0u;
    const int b0 = t * per;
    #pragma unroll
    for (int j = 0; j < 8; ++j){
        unsigned v = 0u;
        if (j < per){ v = hist[b0 + j]; hist[b0 + j] = 0u; }
        c[j] = v; local += v;
    }
    unsigned rank = (mode == 2) ? (unsigned)BETA_K : st->rank;
    s[t] = local;
    __syncthreads();
    #pragma unroll
    for (int off = 1; off < 256; off <<= 1){
        unsigned add = (t + off < 256) ? s[t + off] : 0u;
        __syncthreads();
        s[t] += add;
        __syncthreads();
    }
    unsigned stot   = s[t];
    unsigned sAfter = (t < 255) ? s[t + 1] : 0u;
    if (sAfter < rank && stot >= rank){
        unsigned cum = sAfter;
        int j = per - 1;
        #pragma unroll
        for (int k = 7; k >= 0; --k){
            if (k > per - 1) continue;
            j = k;
            if (cum + c[k] >= rank) break;
            cum += c[k];
        }
        st->rank = rank - cum;
        unsigned kn = (mode == 2) ? 0u : st->known;
        unsigned nk = (kn << dbits) | (unsigned)(b0 + j);
        st->known = nk;
        if (mode == 1) st->thrkey = nk;
    }
}

// ---------------- orchestration ----------------
// ws: t2 32M | B 32M | IB 32M | keys 8M | T 4M | tw 8K | hist 8K | st   (~108 MB)
// d_out (32 MiB) hosts W as f64 during the loop; final kernels overwrite with f32 outputs.
extern "C" void kernel_launch(void* const* d_in, const int* in_sizes, int n_in,
                              void* d_out, int out_size, void* d_ws, size_t ws_size,
                              hipStream_t stream){
    (void)in_sizes; (void)n_in; (void)out_size; (void)ws_size;
    const float2* H = (const float2*)d_in[0];
    const float*  Q = (const float*)d_in[1];
    const float*  zp = (const float*)d_in[2];

    char* ws = (char*)d_ws;
    const size_t A = (size_t)TOT * 16;   // 32 MiB
    c64* t2 = (c64*)(ws);
    c64* B  = (c64*)(ws + A);
    c64* IB = (c64*)(ws + 2*A);
    unsigned int* keys = (unsigned int*)(ws + 3*A);
    c64* T  = (c64*)(ws + 3*A + (size_t)TOT*4);
    c64* tw = (c64*)(ws + 3*A + (size_t)TOT*4 + (size_t)IMGE*16);
    unsigned int* hist = (unsigned int*)((char*)tw + 512*16);
    SelState* st = (SelState*)((char*)hist + 8192);

    c64* Wd = (c64*)d_out;                   // f64 W (32 MiB) during loop
    float2* outW = (float2*)d_out;           // final outputs
    float2* outB = ((float2*)d_out) + TOT;

    hipMemsetAsync(hist, 0, 2048*sizeof(unsigned int), stream);
    k_init<<<IMGE/256, 256, 0, stream>>>(Q, zp, T, tw);

    auto sel = [&](){
        // pass-1 histogram is fused into k_rowB
        k_scan<<<1,256,0,stream>>>(hist, st, 11, 2);
        k_hist<<<1024,256,0,stream>>>(keys, hist, st, 21, 10, 11);
        k_scan<<<1,256,0,stream>>>(hist, st, 11, 0);
        k_hist<<<1024,256,0,stream>>>(keys, hist, st, 10, 0, 10);
        k_scan<<<1,256,0,stream>>>(hist, st, 10, 1);
    };

    // ---- iteration 1 (X=0 -> convXT=0, B0=fft2(ones) delta -> W=1, R=H) ----
    k_colF<<<512,256,0,stream>>>(H, t2, tw);
    k_rowB<<<512,256,0,stream>>>(t2, B, keys, hist, tw);
    sel();
    k_rowMI<<<512,256,0,stream>>>(B, keys, st, t2, tw);
    k_colSIB<true><<<512,256,0,stream>>>(t2, H, Wd, IB, tw);
    k_rowT<true><<<512,256,0,stream>>>(t2, T, tw);
    k_colX<<<512,256,0,stream>>>(t2, tw);

    // ---- iterations 2..5 ----
    for (int iter = 2; iter <= 5; ++iter){
        k_rowT<false><<<512,256,0,stream>>>(t2, T, tw);
        k_colWR<false><<<512,256,0,stream>>>(t2, H, IB, (void*)Wd, tw);
        k_rowB<<<512,256,0,stream>>>(t2, B, keys, hist, tw);
        sel();
        k_rowMI<<<512,256,0,stream>>>(B, keys, st, t2, tw);
        k_colSIB<false><<<512,256,0,stream>>>(t2, H, Wd, IB, tw);
        k_rowT<true><<<512,256,0,stream>>>(t2, T, tw);
        k_colX<<<512,256,0,stream>>>(t2, tw);
    }

    // ---- iteration 6: only W and masked B needed ----
    k_rowT<false><<<512,256,0,stream>>>(t2, T, tw);
    k_colWR<true><<<512,256,0,stream>>>(t2, H, IB, (void*)outW, tw);
    k_rowB<<<512,256,0,stream>>>(t2, B, keys, hist, tw);
    sel();
    k_outB<<<TOT/256,256,0,stream>>>(B, keys, st, outB);
}

// Round 6
// 770.068 us; speedup vs baseline: 4.5232x; 1.3389x over previous
//
#include <hip/hip_runtime.h>
#include <math.h>

// Problem constants
#define NIMG 8
#define MDIM 512
#define IMGE (MDIM*MDIM)        // 262144 per image
#define TOT  (NIMG*IMGE)        // 2097152 complex elements
#define BETA_K 4096
#define LAMD 0.1

typedef double2 c64;

struct SelState { unsigned int known; unsigned int rank; unsigned int thrkey; };

// ---------------- LDS addressing: 8 lines x 512 f64(x2 arrays), XOR swizzle ----------------
__device__ __forceinline__ int LPOS(int ln, int q){
    return (ln << 9) + (q ^ ((((q >> 4) ^ (2 * ln)) & 7) << 1));
}
__device__ __forceinline__ int rev8(int n){   // base-8 digit reversal of 9-bit index
    return ((n & 7) << 6) | (n & 56) | (n >> 6);
}
__device__ __forceinline__ int rde(int w, int k){ // rev8(8w+k)
    return 64*k + 8*(w & 7) + (w >> 3);
}

// ---------------- 8-point DFT in registers. INV=true: conjugate (inverse) ----------------
template<bool INV>
__device__ __forceinline__ void dft8(double* xr, double* xi){
    const double C = 0.70710678118654752440;
    double t0r=xr[0]+xr[4], t0i=xi[0]+xi[4];
    double t1r=xr[0]-xr[4], t1i=xi[0]-xi[4];
    double t2r=xr[2]+xr[6], t2i=xi[2]+xi[6];
    double t3r=xr[2]-xr[6], t3i=xi[2]-xi[6];
    double m3r = INV ? -t3i : t3i;
    double m3i = INV ?  t3r : -t3r;
    double E0r=t0r+t2r, E0i=t0i+t2i;
    double E2r=t0r-t2r, E2i=t0i-t2i;
    double E1r=t1r+m3r, E1i=t1i+m3i;
    double E3r=t1r-m3r, E3i=t1i-m3i;
    double u0r=xr[1]+xr[5], u0i=xi[1]+xi[5];
    double u1r=xr[1]-xr[5], u1i=xi[1]-xi[5];
    double u2r=xr[3]+xr[7], u2i=xi[3]+xi[7];
    double u3r=xr[3]-xr[7], u3i=xi[3]-xi[7];
    double n3r = INV ? -u3i : u3i;
    double n3i = INV ?  u3r : -u3r;
    double O0r=u0r+u2r, O0i=u0i+u2i;
    double O2r=u0r-u2r, O2i=u0i-u2i;
    double O1r=u1r+n3r, O1i=u1i+n3i;
    double O3r=u1r-n3r, O3i=u1i-n3i;
    double W1r = INV ? C*(O1r - O1i) : C*(O1r + O1i);
    double W1i = INV ? C*(O1r + O1i) : C*(O1i - O1r);
    double W2r = INV ? -O2i : O2i;
    double W2i = INV ?  O2r : -O2r;
    double W3r = INV ? -C*(O3r + O3i) : C*(O3i - O3r);
    double W3i = INV ?  C*(O3r - O3i) : -C*(O3r + O3i);
    xr[0]=E0r+O0r; xi[0]=E0i+O0i;  xr[4]=E0r-O0r; xi[4]=E0i-O0i;
    xr[1]=E1r+W1r; xi[1]=E1i+W1i;  xr[5]=E1r-W1r; xi[5]=E1i-W1i;
    xr[2]=E2r+W2r; xi[2]=E2i+W2i;  xr[6]=E2r-W2r; xi[6]=E2i-W2i;
    xr[3]=E3r+W3r; xi[3]=E3i+W3i;  xr[7]=E3r-W3r; xi[7]=E3i-W3i;
}

// ================= ROW-path FFT helpers (register ends) =================
// dit_from_regs: entry: ar[h][k] = input element rev8(8w+k) of line l0+4h.
//                exit:  ar[h][k] = natural-order output element (w + 64k).
template<bool INV>
__device__ __forceinline__ void dit_from_regs(double (&ar)[2][8], double (&ai)[2][8],
                                              double* re, double* im, const c64* __restrict__ tw){
    const int t=threadIdx.x, w=t&63, l0=t>>6;
    #pragma unroll
    for (int h=0;h<2;++h){
        dft8<INV>(ar[h], ai[h]);
        const int ln=l0+4*h;
        #pragma unroll
        for (int k=0;k<8;++k){ int p=LPOS(ln,8*w+k); re[p]=ar[h][k]; im[p]=ai[h][k]; }
    }
    __syncthreads();
    {   // stage 1: groups 64g+j+8k, twiddle tw[8jk]
        const int g=w>>3, j=w&7;
        double wr[8], wi[8];
        #pragma unroll
        for (int k=1;k<8;++k){ c64 tv=tw[8*j*k]; wr[k]=tv.x; wi[k]=INV?-tv.y:tv.y; }
        #pragma unroll
        for (int h=0;h<2;++h){
            const int ln=l0+4*h;
            double xr[8], xi[8];
            #pragma unroll
            for (int k=0;k<8;++k){ int p=LPOS(ln,64*g+j+8*k); double a=re[p],b=im[p];
                if(k==0){xr[0]=a; xi[0]=b;} else {xr[k]=a*wr[k]-b*wi[k]; xi[k]=a*wi[k]+b*wr[k];} }
            dft8<INV>(xr,xi);
            #pragma unroll
            for (int k=0;k<8;++k){ int p=LPOS(ln,64*g+j+8*k); re[p]=xr[k]; im[p]=xi[k]; }
        }
    }
    __syncthreads();
    {   // stage 2 -> regs: groups j+64k, twiddle tw[jk]
        const int j=w;
        double wr[8], wi[8];
        #pragma unroll
        for (int k=1;k<8;++k){ c64 tv=tw[j*k]; wr[k]=tv.x; wi[k]=INV?-tv.y:tv.y; }
        #pragma unroll
        for (int h=0;h<2;++h){
            const int ln=l0+4*h;
            #pragma unroll
            for (int k=0;k<8;++k){ int p=LPOS(ln,j+64*k); double a=re[p],b=im[p];
                if(k==0){ar[h][0]=a; ai[h][0]=b;} else {ar[h][k]=a*wr[k]-b*wi[k]; ai[h][k]=a*wi[k]+b*wr[k];} }
            dft8<INV>(ar[h], ai[h]);
        }
    }
}

// dif_to_regs: entry: ar[h][k] = natural element (w + 64k) of line l0+4h.
//              exit:  ar[h][k] = output element rev8(8w+k) = rde(w,k).
template<bool INV>
__device__ __forceinline__ void dif_to_regs(double (&ar)[2][8], double (&ai)[2][8],
                                            double* re, double* im, const c64* __restrict__ tw){
    const int t=threadIdx.x, w=t&63, l0=t>>6;
    {   // stage A (from regs): dft8, post-twiddle tw[w*k], write at j+64k
        const int j=w;
        double wr[8], wi[8];
        #pragma unroll
        for (int k=1;k<8;++k){ c64 tv=tw[j*k]; wr[k]=tv.x; wi[k]=INV?-tv.y:tv.y; }
        #pragma unroll
        for (int h=0;h<2;++h){
            dft8<INV>(ar[h], ai[h]);
            const int ln=l0+4*h;
            #pragma unroll
            for (int k=0;k<8;++k){
                int p=LPOS(ln,j+64*k);
                if(k==0){ re[p]=ar[h][0]; im[p]=ai[h][0]; }
                else { re[p]=ar[h][k]*wr[k]-ai[h][k]*wi[k]; im[p]=ar[h][k]*wi[k]+ai[h][k]*wr[k]; }
            }
        }
    }
    __syncthreads();
    {   // stage B: groups 64g+j+8k, post-twiddle tw[8jk]
        const int g=w>>3, j=w&7;
        double wr[8], wi[8];
        #pragma unroll
        for (int k=1;k<8;++k){ c64 tv=tw[8*j*k]; wr[k]=tv.x; wi[k]=INV?-tv.y:tv.y; }
        #pragma unroll
        for (int h=0;h<2;++h){
            const int ln=l0+4*h;
            double xr[8], xi[8];
            #pragma unroll
            for (int k=0;k<8;++k){ int p=LPOS(ln,64*g+j+8*k); xr[k]=re[p]; xi[k]=im[p]; }
            dft8<INV>(xr,xi);
            #pragma unroll
            for (int k=0;k<8;++k){
                int p=LPOS(ln,64*g+j+8*k);
                if(k==0){ re[p]=xr[0]; im[p]=xi[0]; }
                else { re[p]=xr[k]*wr[k]-xi[k]*wi[k]; im[p]=xr[k]*wi[k]+xi[k]*wr[k]; }
            }
        }
    }
    __syncthreads();
    // stage C -> regs (no twiddle)
    #pragma unroll
    for (int h=0;h<2;++h){
        const int ln=l0+4*h;
        #pragma unroll
        for (int k=0;k<8;++k){ int p=LPOS(ln,8*w+k); ar[h][k]=re[p]; ai[h][k]=im[p]; }
        dft8<INV>(ar[h], ai[h]);
    }
}

// ================= COL-path FFT (full-LDS) =================
template<bool INV>
__device__ void r8_dit(double* re, double* im, const c64* __restrict__ tw){
    const int t = threadIdx.x;
    const int w = t & 63;
    const int l0 = t >> 6;
    __syncthreads();
    #pragma unroll
    for (int h = 0; h < 2; ++h){
        const int ln = l0 + 4*h;
        double xr[8], xi[8];
        #pragma unroll
        for (int k = 0; k < 8; ++k){ int p = LPOS(ln, 8*w + k); xr[k]=re[p]; xi[k]=im[p]; }
        dft8<INV>(xr, xi);
        #pragma unroll
        for (int k = 0; k < 8; ++k){ int p = LPOS(ln, 8*w + k); re[p]=xr[k]; im[p]=xi[k]; }
    }
    {
        const int g = w >> 3, j = w & 7;
        double wr[8], wi[8];
        #pragma unroll
        for (int k = 1; k < 8; ++k){ c64 tv = tw[8*j*k]; wr[k]=tv.x; wi[k]= INV ? -tv.y : tv.y; }
        __syncthreads();
        #pragma unroll
        for (int h = 0; h < 2; ++h){
            const int ln = l0 + 4*h;
            double xr[8], xi[8];
            #pragma unroll
            for (int k = 0; k < 8; ++k){
                int p = LPOS(ln, 64*g + j + 8*k); double ar=re[p], ai=im[p];
                if (k == 0){ xr[0]=ar; xi[0]=ai; }
                else { xr[k]=ar*wr[k]-ai*wi[k]; xi[k]=ar*wi[k]+ai*wr[k]; }
            }
            dft8<INV>(xr, xi);
            #pragma unroll
            for (int k = 0; k < 8; ++k){ int p = LPOS(ln, 64*g + j + 8*k); re[p]=xr[k]; im[p]=xi[k]; }
        }
    }
    {
        const int j = w;
        double wr[8], wi[8];
        #pragma unroll
        for (int k = 1; k < 8; ++k){ c64 tv = tw[j*k]; wr[k]=tv.x; wi[k]= INV ? -tv.y : tv.y; }
        __syncthreads();
        #pragma unroll
        for (int h = 0; h < 2; ++h){
            const int ln = l0 + 4*h;
            double xr[8], xi[8];
            #pragma unroll
            for (int k = 0; k < 8; ++k){
                int p = LPOS(ln, j + 64*k); double ar=re[p], ai=im[p];
                if (k == 0){ xr[0]=ar; xi[0]=ai; }
                else { xr[k]=ar*wr[k]-ai*wi[k]; xi[k]=ar*wi[k]+ai*wr[k]; }
            }
            dft8<INV>(xr, xi);
            #pragma unroll
            for (int k = 0; k < 8; ++k){ int p = LPOS(ln, j + 64*k); re[p]=xr[k]; im[p]=xi[k]; }
        }
    }
}

template<bool INV>
__device__ void r8_dif(double* re, double* im, const c64* __restrict__ tw){
    const int t = threadIdx.x;
    const int w = t & 63;
    const int l0 = t >> 6;
    {
        const int j = w;
        double wr[8], wi[8];
        #pragma unroll
        for (int k = 1; k < 8; ++k){ c64 tv = tw[j*k]; wr[k]=tv.x; wi[k]= INV ? -tv.y : tv.y; }
        __syncthreads();
        #pragma unroll
        for (int h = 0; h < 2; ++h){
            const int ln = l0 + 4*h;
            double xr[8], xi[8];
            #pragma unroll
            for (int k = 0; k < 8; ++k){ int p = LPOS(ln, j + 64*k); xr[k]=re[p]; xi[k]=im[p]; }
            dft8<INV>(xr, xi);
            #pragma unroll
            for (int k = 0; k < 8; ++k){
                int p = LPOS(ln, j + 64*k);
                if (k == 0){ re[p]=xr[0]; im[p]=xi[0]; }
                else { re[p]=xr[k]*wr[k]-xi[k]*wi[k]; im[p]=xr[k]*wi[k]+xi[k]*wr[k]; }
            }
        }
    }
    {
        const int g = w >> 3, j = w & 7;
        double wr[8], wi[8];
        #pragma unroll
        for (int k = 1; k < 8; ++k){ c64 tv = tw[8*j*k]; wr[k]=tv.x; wi[k]= INV ? -tv.y : tv.y; }
        __syncthreads();
        #pragma unroll
        for (int h = 0; h < 2; ++h){
            const int ln = l0 + 4*h;
            double xr[8], xi[8];
            #pragma unroll
            for (int k = 0; k < 8; ++k){ int p = LPOS(ln, 64*g + j + 8*k); xr[k]=re[p]; xi[k]=im[p]; }
            dft8<INV>(xr, xi);
            #pragma unroll
            for (int k = 0; k < 8; ++k){
                int p = LPOS(ln, 64*g + j + 8*k);
                if (k == 0){ re[p]=xr[0]; im[p]=xi[0]; }
                else { re[p]=xr[k]*wr[k]-xi[k]*wi[k]; im[p]=xr[k]*wi[k]+xi[k]*wr[k]; }
            }
        }
    }
    __syncthreads();
    #pragma unroll
    for (int h = 0; h < 2; ++h){
        const int ln = l0 + 4*h;
        double xr[8], xi[8];
        #pragma unroll
        for (int k = 0; k < 8; ++k){ int p = LPOS(ln, 8*w + k); xr[k]=re[p]; xi[k]=im[p]; }
        dft8<INV>(xr, xi);
        #pragma unroll
        for (int k = 0; k < 8; ++k){ int p = LPOS(ln, 8*w + k); re[p]=xr[k]; im[p]=xi[k]; }
    }
}

__device__ __forceinline__ void col_load32(const float2* __restrict__ src, size_t base,
                                           double* re, double* im){
    const int t = threadIdx.x;
    #pragma unroll
    for (int it = 0; it < 16; ++it){
        int idx = it*256 + t; int ln = idx & 7, e = idx >> 3;
        float2 v = src[base + ln + (size_t)e*512];
        int p = LPOS(ln, rev8(e));
        re[p] = (double)v.x; im[p] = (double)v.y;
    }
}

// ---------------- init: T = exp(i*(z/WL)*Q) (f64), twiddles (f64) ----------------
__global__ __launch_bounds__(256) void k_init(const float* __restrict__ Q,
                                              const float* __restrict__ zp,
                                              c64* __restrict__ T,
                                              c64* __restrict__ tw){
    int i = blockIdx.x*256 + threadIdx.x;
    if (i < IMGE){
        double a = ((double)zp[0] / 6.37e-07) * (double)Q[i];
        T[i] = make_double2(cos(a), sin(a));
    }
    if (i < 512){
        double a = -6.283185307179586476925286766559 * ((double)i / 512.0);
        tw[i] = make_double2(cos(a), sin(a));
    }
}

// ---------------- k_colF (iter 1): forward col FFT of H -> t2 ----------------
__global__ __launch_bounds__(256,2) void k_colF(const float2* __restrict__ H,
                                                float2* __restrict__ t2,
                                                const c64* __restrict__ tw){
    __shared__ double re[4096]; __shared__ double im[4096];
    const int t = threadIdx.x, blk = blockIdx.x;
    const size_t base = (size_t)(blk >> 6) * IMGE + (size_t)(blk & 63) * 8;
    col_load32(H, base, re, im);
    r8_dit<false>(re, im, tw);
    __syncthreads();
    #pragma unroll
    for (int it = 0; it < 16; ++it){
        int idx = it*256 + t; int ln = idx & 7, e = idx >> 3;
        int p = LPOS(ln, e);
        t2[base + ln + (size_t)e*512] = make_float2((float)re[p], (float)im[p]);
    }
}

// ---------------- kA: rowI(G + Bmasked) -> t2 (x1/512) ----------------
__global__ __launch_bounds__(256,2) void k_rowA(const float2* __restrict__ B,
                                                const unsigned int* __restrict__ keys,
                                                const SelState* __restrict__ st,
                                                const float2* __restrict__ G,
                                                float2* __restrict__ t2,
                                                const c64* __restrict__ tw){
    __shared__ double re[4096]; __shared__ double im[4096];
    const int t = threadIdx.x, blk = blockIdx.x;
    const int w = t & 63, l0 = t >> 6;
    const size_t base = (size_t)blk * 4096;
    const unsigned int thr = st->thrkey;
    double ar[2][8], ai[2][8];
    #pragma unroll
    for (int h=0;h<2;++h){ const int ln=l0+4*h;
        #pragma unroll
        for (int k=0;k<8;++k){
            size_t addr = base + ln*512 + (w + 64*k);
            float2 g = G[addr];
            float2 b = B[addr];
            bool keep = keys[addr] >= thr;        // Bm = top-k kept
            ar[h][k] = (double)g.x + (keep ? (double)b.x : 0.0);
            ai[h][k] = (double)g.y + (keep ? (double)b.y : 0.0);
        } }
    dif_to_regs<true>(ar, ai, re, im, tw);
    const double sc = 1.0/512.0;
    #pragma unroll
    for (int h=0;h<2;++h){ const int ln=l0+4*h;
        #pragma unroll
        for (int k=0;k<8;++k)
            t2[base + ln*512 + rde(w,k)] = make_float2((float)(ar[h][k]*sc), (float)(ai[h][k]*sc)); }
}

// ---------------- kB: colI -> W=normalize(Z) -> Qc=H*W -> colF(Qc) ----------------
template<bool FINAL>
__global__ __launch_bounds__(256,2) void k_colWQ(float2* __restrict__ t2,
                                                 const float2* __restrict__ H,
                                                 float2* __restrict__ outW,
                                                 const c64* __restrict__ tw){
    __shared__ double re[4096]; __shared__ double im[4096];
    const int t = threadIdx.x, blk = blockIdx.x;
    const size_t base = (size_t)(blk >> 6) * IMGE + (size_t)(blk & 63) * 8;
    col_load32(t2, base, re, im);
    r8_dit<true>(re, im, tw);          // inverse col FFT (unscaled here)
    __syncthreads();
    const double sc = 1.0/512.0;
    #pragma unroll
    for (int it = 0; it < 16; ++it){
        int idx = it*256 + t; int ln = idx & 7, e = idx >> 3;
        size_t addr = base + ln + (size_t)e*512;
        int p = LPOS(ln, e);
        double zr = re[p]*sc, zi = im[p]*sc;   // Z = convXT + IB (spatial)
        double m = sqrt(zr*zr + zi*zi);
        double d = (m == 0.0) ? 1.0 : m;
        double wx = zr/d, wy = zi/d;           // W = normalize(Z)
        if (FINAL) outW[addr] = make_float2((float)wx, (float)wy);
        float2 h = H[addr];
        re[p] = (double)h.x*wx - (double)h.y*wy;   // Qc = H*W
        im[p] = (double)h.x*wy + (double)h.y*wx;
    }
    r8_dif<false>(re, im, tw);         // forward col FFT of Qc
    __syncthreads();
    #pragma unroll
    for (int it = 0; it < 16; ++it){
        int idx = it*256 + t; int ln = idx & 7, e = idx >> 3;
        int p = LPOS(ln, rev8(e));
        t2[base + ln + (size_t)e*512] = make_float2((float)re[p], (float)im[p]);
    }
}

// ---------------- kC: rowF -> B = FQc - G -> store B/keys + fused hist pass-1 ----------------
template<bool G0>
__global__ __launch_bounds__(256,2) void k_rowC(const float2* __restrict__ t2,
                                                const float2* __restrict__ G,
                                                float2* __restrict__ B,
                                                unsigned int* __restrict__ keys,
                                                unsigned int* __restrict__ hist,
                                                const c64* __restrict__ tw){
    __shared__ double re[4096]; __shared__ double im[4096];
    const int t = threadIdx.x, blk = blockIdx.x;
    const int w = t & 63, l0 = t >> 6;
    const size_t base = (size_t)blk * 4096;
    double ar[2][8], ai[2][8];
    #pragma unroll
    for (int h=0;h<2;++h){ const int ln=l0+4*h;
        #pragma unroll
        for (int k=0;k<8;++k){ float2 v = t2[base + ln*512 + rde(w,k)];
            ar[h][k]=(double)v.x; ai[h][k]=(double)v.y; } }
    dit_from_regs<false>(ar, ai, re, im, tw);
    __syncthreads();                   // stage-2 LDS reads done -> reuse re as hist
    unsigned int* lh = reinterpret_cast<unsigned int*>(re);
    for (int b = t; b < 2048; b += 256) lh[b] = 0u;
    __syncthreads();
    #pragma unroll
    for (int h=0;h<2;++h){
        const int ln=l0+4*h;
        #pragma unroll
        for (int k=0;k<8;++k){
            size_t addr = base + ln*512 + (w + 64*k);
            double br = ar[h][k], bi = ai[h][k];
            if (!G0){ float2 g = G[addr]; br -= (double)g.x; bi -= (double)g.y; }
            B[addr] = make_float2((float)br, (float)bi);
            unsigned int key = __float_as_uint((float)sqrt(br*br + bi*bi));
            keys[addr] = key;
            atomicAdd(&lh[key >> 21], 1u);
        }
    }
    __syncthreads();
    for (int b = t; b < 2048; b += 256){
        unsigned int v = lh[b];
        if (v) atomicAdd(&hist[b], v);
    }
}

// ---------------- kD: E = (B*(1-mask) + G)*conj(T) -> rowI -> t2 (x1/512) ----------------
template<bool G0>
__global__ __launch_bounds__(256,2) void k_rowD(const float2* __restrict__ B,
                                                const unsigned int* __restrict__ keys,
                                                const SelState* __restrict__ st,
                                                const float2* __restrict__ G,
                                                const c64* __restrict__ T,
                                                float2* __restrict__ t2,
                                                const c64* __restrict__ tw){
    __shared__ double re[4096]; __shared__ double im[4096];
    const int t = threadIdx.x, blk = blockIdx.x;
    const int w = t & 63, l0 = t >> 6;
    const size_t base = (size_t)blk * 4096;
    const unsigned int thr = st->thrkey;
    double ar[2][8], ai[2][8];
    #pragma unroll
    for (int h=0;h<2;++h){
        const int ln=l0+4*h;
        const int u = (blk & 63) * 8 + ln;
        #pragma unroll
        for (int k=0;k<8;++k){
            const int e = w + 64*k;
            size_t addr = base + ln*512 + e;
            float2 b = B[addr];
            bool lo = keys[addr] < thr;           // complement of top-k mask
            double vr = lo ? (double)b.x : 0.0;
            double vi = lo ? (double)b.y : 0.0;
            if (!G0){ float2 g = G[addr]; vr += (double)g.x; vi += (double)g.y; }
            c64 tv = T[u*512 + e];
            ar[h][k] = vr*tv.x + vi*tv.y;         // * conj(T)
            ai[h][k] = vi*tv.x - vr*tv.y;
        }
    }
    dif_to_regs<true>(ar, ai, re, im, tw);
    const double sc = 1.0/512.0;
    #pragma unroll
    for (int h=0;h<2;++h){ const int ln=l0+4*h;
        #pragma unroll
        for (int k=0;k<8;++k)
            t2[base + ln*512 + rde(w,k)] = make_float2((float)(ar[h][k]*sc), (float)(ai[h][k]*sc)); }
}

// ---------------- kE: colI -> X = inp1*(|inp1|>LAM) -> colF(X) ----------------
__global__ __launch_bounds__(256,2) void k_colX(float2* __restrict__ t2,
                                                const c64* __restrict__ tw){
    __shared__ double re[4096]; __shared__ double im[4096];
    const int t = threadIdx.x, blk = blockIdx.x;
    const size_t base = (size_t)(blk >> 6) * IMGE + (size_t)(blk & 63) * 8;
    col_load32(t2, base, re, im);
    r8_dit<true>(re, im, tw);
    __syncthreads();
    const double sc = 1.0/512.0;
    #pragma unroll
    for (int it = 0; it < 16; ++it){
        int idx = it*256 + t;
        int p = LPOS(idx & 7, idx >> 3);
        double vr = re[p]*sc, vi = im[p]*sc;      // inp1
        double m = sqrt(vr*vr + vi*vi);
        bool keep = m > LAMD;
        re[p] = keep ? vr : 0.0;
        im[p] = keep ? vi : 0.0;
    }
    r8_dif<false>(re, im, tw);
    __syncthreads();
    #pragma unroll
    for (int it = 0; it < 16; ++it){
        int idx = it*256 + t; int ln = idx & 7, e = idx >> 3;
        int p = LPOS(ln, rev8(e));
        t2[base + ln + (size_t)e*512] = make_float2((float)re[p], (float)im[p]);
    }
}

// ---------------- kF: rowF(X) -> G = FX*T ----------------
__global__ __launch_bounds__(256,2) void k_rowF(const float2* __restrict__ t2,
                                                const c64* __restrict__ T,
                                                float2* __restrict__ G,
                                                const c64* __restrict__ tw){
    __shared__ double re[4096]; __shared__ double im[4096];
    const int t = threadIdx.x, blk = blockIdx.x;
    const int w = t & 63, l0 = t >> 6;
    const size_t base = (size_t)blk * 4096;
    double ar[2][8], ai[2][8];
    #pragma unroll
    for (int h=0;h<2;++h){ const int ln=l0+4*h;
        #pragma unroll
        for (int k=0;k<8;++k){ float2 v = t2[base + ln*512 + rde(w,k)];
            ar[h][k]=(double)v.x; ai[h][k]=(double)v.y; } }
    dit_from_regs<false>(ar, ai, re, im, tw);
    #pragma unroll
    for (int h=0;h<2;++h){
        const int ln=l0+4*h;
        const int u = (blk & 63) * 8 + ln;
        #pragma unroll
        for (int k=0;k<8;++k){
            const int e = w + 64*k;
            size_t addr = base + ln*512 + e;
            c64 tv = T[u*512 + e];
            double xr = ar[h][k], xi = ai[h][k];
            G[addr] = make_float2((float)(xr*tv.x - xi*tv.y), (float)(xr*tv.y + xi*tv.x));
        }
    }
}

// ---------------- final masked B -> d_out second half ----------------
__global__ __launch_bounds__(256) void k_outB(const float2* __restrict__ B,
                                              const unsigned int* __restrict__ keys,
                                              const SelState* __restrict__ st,
                                              float2* __restrict__ outB){
    int i = blockIdx.x*256 + threadIdx.x;
    float2 v = B[i];
    if (keys[i] < st->thrkey) v = make_float2(0.0f, 0.0f);
    outB[i] = v;
}

// ---------------- radix select: filtered histogram + parallel scan ----------------
__global__ __launch_bounds__(256) void k_hist(const unsigned int* __restrict__ keys,
                                              unsigned int* __restrict__ hist,
                                              const SelState* __restrict__ st,
                                              int shiftHi, int shift, int dbits){
    __shared__ unsigned int lh[2048];
    int t = threadIdx.x;
    int nd = 1 << dbits;
    for (int b = t; b < nd; b += 256) lh[b] = 0u;
    __syncthreads();
    unsigned known = st->known;
    unsigned msk = (unsigned)((1u << dbits) - 1u);
    for (int i = blockIdx.x*256 + t; i < TOT; i += gridDim.x*256){
        unsigned k = keys[i];
        if ((k >> shiftHi) == known) atomicAdd(&lh[(k >> shift) & msk], 1u);
    }
    __syncthreads();
    for (int b = t; b < nd; b += 256){
        unsigned v = lh[b];
        if (v) atomicAdd(&hist[b], v);
    }
}

// mode: 2=first pass (rank=BETA, known=0), 0=middle, 1=last (writes thrkey).
__global__ __launch_bounds__(256) void k_scan(unsigned int* __restrict__ hist,
                                              SelState* __restrict__ st,
                                              int dbits, int mode){
    __shared__ unsigned int s[256];
    const int t = threadIdx.x;
    const int nd = 1 << dbits;
    const int per = nd >> 8;
    unsigned c[8];
    unsigned local = 0u;
    const int b0 = t * per;
    #pragma unroll
    for (int j = 0; j < 8; ++j){
        unsigned v = 0u;
        if (j < per){ v = hist[b0 + j]; hist[b0 + j] = 0u; }
        c[j] = v; local += v;
    }
    unsigned rank = (mode == 2) ? (unsigned)BETA_K : st->rank;
    s[t] = local;
    __syncthreads();
    #pragma unroll
    for (int off = 1; off < 256; off <<= 1){
        unsigned add = (t + off < 256) ? s[t + off] : 0u;
        __syncthreads();
        s[t] += add;
        __syncthreads();
    }
    unsigned stot   = s[t];
    unsigned sAfter = (t < 255) ? s[t + 1] : 0u;
    if (sAfter < rank && stot >= rank){
        unsigned cum = sAfter;
        int j = per - 1;
        #pragma unroll
        for (int k = 7; k >= 0; --k){
            if (k > per - 1) continue;
            j = k;
            if (cum + c[k] >= rank) break;
            cum += c[k];
        }
        st->rank = rank - cum;
        unsigned kn = (mode == 2) ? 0u : st->known;
        unsigned nk = (kn << dbits) | (unsigned)(b0 + j);
        st->known = nk;
        if (mode == 1) st->thrkey = nk;
    }
}

// ---------------- orchestration ----------------
// Freq-domain formulation: G = fft2(X)*T.
//   W   = normalize(ifft2(G + Bm_prev))
//   B   = fft2(H*W) - G
//   E   = (B*(1-mask) + G)*conj(T);  inp1 = ifft2(E);  X = thresh(inp1)
//   G'  = fft2(X)*T
// ws (f32 arrays, f64 tables): t2 16M | B 16M | G 16M | keys 8M | T 4M | tw | hist | st  (~60 MB)
extern "C" void kernel_launch(void* const* d_in, const int* in_sizes, int n_in,
                              void* d_out, int out_size, void* d_ws, size_t ws_size,
                              hipStream_t stream){
    (void)in_sizes; (void)n_in; (void)out_size; (void)ws_size;
    const float2* H = (const float2*)d_in[0];
    const float*  Q = (const float*)d_in[1];
    const float*  zp = (const float*)d_in[2];

    char* ws = (char*)d_ws;
    const size_t A = (size_t)TOT * sizeof(float2);   // 16 MiB
    float2* t2 = (float2*)(ws);
    float2* B  = (float2*)(ws + A);
    float2* G  = (float2*)(ws + 2*A);
    unsigned int* keys = (unsigned int*)(ws + 3*A);              // 8 MiB
    c64* T  = (c64*)(ws + 3*A + (size_t)TOT*4);                  // 4 MiB
    c64* tw = (c64*)(ws + 3*A + (size_t)TOT*4 + (size_t)IMGE*16);
    unsigned int* hist = (unsigned int*)((char*)tw + 512*16);
    SelState* st = (SelState*)((char*)hist + 8192);

    float2* outW = (float2*)d_out;
    float2* outB = ((float2*)d_out) + TOT;

    hipMemsetAsync(hist, 0, 2048*sizeof(unsigned int), stream);
    k_init<<<IMGE/256, 256, 0, stream>>>(Q, zp, T, tw);

    auto sel = [&](){
        // pass-1 histogram fused into k_rowC
        k_scan<<<1,256,0,stream>>>(hist, st, 11, 2);
        k_hist<<<1024,256,0,stream>>>(keys, hist, st, 21, 10, 11);
        k_scan<<<1,256,0,stream>>>(hist, st, 11, 0);
        k_hist<<<1024,256,0,stream>>>(keys, hist, st, 10, 0, 10);
        k_scan<<<1,256,0,stream>>>(hist, st, 10, 1);
    };

    // ---- iteration 1: X=0 -> G=0, W=1 -> Qc=H ----
    k_colF<<<512,256,0,stream>>>(H, t2, tw);                    // t2 = colF(H)
    k_rowC<true><<<512,256,0,stream>>>(t2, G, B, keys, hist, tw);  // B = fft2(H)
    sel();
    k_rowD<true><<<512,256,0,stream>>>(B, keys, st, G, T, t2, tw); // E=B(1-m)*conjT, rowI
    k_colX<<<512,256,0,stream>>>(t2, tw);                       // colI -> thresh -> colF
    k_rowF<<<512,256,0,stream>>>(t2, T, G, tw);                 // G = fft2(X)*T

    // ---- iterations 2..5 ----
    for (int iter = 2; iter <= 5; ++iter){
        k_rowA<<<512,256,0,stream>>>(B, keys, st, G, t2, tw);   // rowI(G + Bm)
        k_colWQ<false><<<512,256,0,stream>>>(t2, H, outW, tw);  // W, Qc, colF(Qc)
        k_rowC<false><<<512,256,0,stream>>>(t2, G, B, keys, hist, tw); // B = FQc - G
        sel();
        k_rowD<false><<<512,256,0,stream>>>(B, keys, st, G, T, t2, tw);
        k_colX<<<512,256,0,stream>>>(t2, tw);
        k_rowF<<<512,256,0,stream>>>(t2, T, G, tw);
    }

    // ---- iteration 6: only W and masked B needed ----
    k_rowA<<<512,256,0,stream>>>(B, keys, st, G, t2, tw);
    k_colWQ<true><<<512,256,0,stream>>>(t2, H, outW, tw);       // stores final W
    k_rowC<false><<<512,256,0,stream>>>(t2, G, B, keys, hist, tw);
    sel();
    k_outB<<<TOT/256,256,0,stream>>>(B, keys, st, outB);
}